// Round 4
// baseline (339.955 us; speedup 1.0000x reference)
//
#include <hip/hip_runtime.h>
#include <math.h>

#define NB 16
#define NN 768
#define NT 48
#define ND 2048
#define SCALE 0.02209708691207961f   // 1/sqrt(2048)
#define NEGBIG (-3.4028234663852886e38f)
#define TAU 2e-4f

typedef _Float16 f16;
typedef f16  f16x8 __attribute__((ext_vector_type(8)));
typedef f16  f16x4 __attribute__((ext_vector_type(4)));
typedef float f32x4 __attribute__((ext_vector_type(4)));

__device__ __forceinline__ void stage16(const void* g, void* l) {
    __builtin_amdgcn_global_load_lds(
        (const __attribute__((address_space(1))) unsigned int*)g,
        (__attribute__((address_space(3))) unsigned int*)l, 16, 0, 0);
}

// ---------------- kernel 1: task rms-norm + fp16 hi/lo split ----------------
__global__ __launch_bounds__(256) void k_prep_task(const float* __restrict__ task,
                                                   f16* __restrict__ t_hi,
                                                   f16* __restrict__ t_lo) {
    __shared__ float sred[8];
    const int row = blockIdx.x;                 // b*NT + t
    const float4* src = (const float4*)(task + (size_t)row * ND);
    const int tid = threadIdx.x;
    float4 v0 = src[tid];
    float4 v1 = src[tid + 256];
    float s = v0.x*v0.x + v0.y*v0.y + v0.z*v0.z + v0.w*v0.w
            + v1.x*v1.x + v1.y*v1.y + v1.z*v1.z + v1.w*v1.w;
    #pragma unroll
    for (int off = 32; off > 0; off >>= 1) s += __shfl_down(s, off, 64);
    if ((tid & 63) == 0) sred[tid >> 6] = s;
    __syncthreads();
    if (tid == 0)
        sred[4] = 1.0f / sqrtf((sred[0]+sred[1]+sred[2]+sred[3]) * (1.0f/ND) + 1e-6f);
    __syncthreads();
    const float inv = sred[4];
    f16x4 h0, l0, h1, l1;
    #pragma unroll
    for (int e = 0; e < 4; e++) {
        float f0 = (&v0.x)[e] * inv, f1 = (&v1.x)[e] * inv;
        f16 a = (f16)f0; h0[e] = a; l0[e] = (f16)(f0 - (float)a);
        f16 c = (f16)f1; h1[e] = c; l1[e] = (f16)(f1 - (float)c);
    }
    const size_t o = (size_t)row * ND;
    *(f16x4*)&t_hi[o + tid*4] = h0;
    *(f16x4*)&t_lo[o + tid*4] = l0;
    *(f16x4*)&t_hi[o + tid*4 + 1024] = h1;
    *(f16x4*)&t_lo[o + tid*4 + 1024] = l1;
}

// ---------------- kernel 2: pinv + fp16 hi/lo split of patches ----------------
__global__ __launch_bounds__(256) void k_split_p(const float* __restrict__ x,
                                                 float* __restrict__ pinv,
                                                 f16* __restrict__ p_hi,
                                                 f16* __restrict__ p_lo) {
    __shared__ float sred[8];
    const int row = blockIdx.x;                 // b*NN + n
    const float4* src = (const float4*)(x + (size_t)row * ND);
    const int tid = threadIdx.x;
    float4 v0 = src[tid];
    float4 v1 = src[tid + 256];
    float s = v0.x*v0.x + v0.y*v0.y + v0.z*v0.z + v0.w*v0.w
            + v1.x*v1.x + v1.y*v1.y + v1.z*v1.z + v1.w*v1.w;
    #pragma unroll
    for (int off = 32; off > 0; off >>= 1) s += __shfl_down(s, off, 64);
    if ((tid & 63) == 0) sred[tid >> 6] = s;
    __syncthreads();
    if (tid == 0)
        pinv[row] = 1.0f / sqrtf((sred[0]+sred[1]+sred[2]+sred[3]) * (1.0f/ND) + 1e-6f);
    f16x4 h0, l0, h1, l1;
    #pragma unroll
    for (int e = 0; e < 4; e++) {
        float f0 = (&v0.x)[e], f1 = (&v1.x)[e];
        f16 a = (f16)f0; h0[e] = a; l0[e] = (f16)(f0 - (float)a);
        f16 c = (f16)f1; h1[e] = c; l1[e] = (f16)(f1 - (float)c);
    }
    const size_t o = (size_t)row * ND;
    *(f16x4*)&p_hi[o + tid*4] = h0;
    *(f16x4*)&p_lo[o + tid*4] = l0;
    *(f16x4*)&p_hi[o + (tid+256)*4] = h1;
    *(f16x4*)&p_lo[o + (tid+256)*4] = l1;
}

// ---------------- kernel 3: logits MFMA (3-pass) + softmax -> w_hi/w_lo ----------------
// tile 192 rows x 48 task cols, 4 waves (wave = 48x48). grid (4 rt, 16 b).
__global__ __launch_bounds__(256) void k_logits(const f16* __restrict__ p_hi,
                                                const f16* __restrict__ p_lo,
                                                const f16* __restrict__ t_hi,
                                                const f16* __restrict__ t_lo,
                                                const float* __restrict__ pinv,
                                                const int* __restrict__ mask,
                                                f16* __restrict__ w_hi,
                                                f16* __restrict__ w_lo) {
    __shared__ __align__(16) char Ast[192*128];   // 192 rows x 128B (64 f16)
    __shared__ __align__(16) char Bst[48*128];
    const int rt = blockIdx.x, b = blockIdx.y;
    const int r0 = rt * 192;
    const int tid = threadIdx.x, wid = tid >> 6, lane = tid & 63;
    const int q15 = lane & 15, g4 = lane >> 4;
    const int lr = lane >> 3, lgch = (lane & 7) ^ lr;

    const f16* gAh = p_hi + (size_t)(b*NN + r0) * ND;
    const f16* gAl = p_lo + (size_t)(b*NN + r0) * ND;
    const f16* gBh = t_hi + (size_t)b * NT * ND;
    const f16* gBl = t_lo + (size_t)b * NT * ND;

    f32x4 acc[3][3];
    #pragma unroll
    for (int i = 0; i < 3; i++)
        #pragma unroll
        for (int j = 0; j < 3; j++) acc[i][j] = (f32x4){0.f,0.f,0.f,0.f};

    const int cxor = q15 & 7;
    for (int s = 0; s < 96; s++) {
        const int pass = s >> 5;
        const f16* gA = (pass == 1) ? gAl : gAh;
        const f16* gB = (pass == 2) ? gBl : gBh;
        const int kofs = (s & 31) * 64;
        #pragma unroll
        for (int ti = 0; ti < 6; ti++) {
            const int u = wid*6 + ti;
            stage16(gA + (size_t)(u*8 + lr)*ND + kofs + lgch*8, Ast + u*1024);
        }
        #pragma unroll
        for (int t2 = 0; t2 < 2; t2++) {
            const int u = wid + 4*t2;
            if (u < 6)
                stage16(gB + (size_t)(u*8 + lr)*ND + kofs + lgch*8, Bst + u*1024);
        }
        __syncthreads();
        #pragma unroll
        for (int ksub = 0; ksub < 2; ksub++) {
            const int chb = ((ksub*4 + g4) ^ cxor) << 4;
            f16x8 ah[3], bh[3];
            #pragma unroll
            for (int i = 0; i < 3; i++)
                ah[i] = *(const f16x8*)(Ast + (wid*48 + i*16 + q15)*128 + chb);
            #pragma unroll
            for (int j = 0; j < 3; j++)
                bh[j] = *(const f16x8*)(Bst + (j*16 + q15)*128 + chb);
            #pragma unroll
            for (int i = 0; i < 3; i++)
                #pragma unroll
                for (int j = 0; j < 3; j++)
                    acc[i][j] = __builtin_amdgcn_mfma_f32_16x16x32_f16(ah[i], bh[j], acc[i][j], 0, 0, 0);
        }
        __syncthreads();
    }

    // epilogue: scale + bias, row softmax (16-lane groups), write w hi/lo
    float bias[3];
    #pragma unroll
    for (int j = 0; j < 3; j++)
        bias[j] = mask[b*NT + j*16 + q15] ? 0.0f : NEGBIG;
    #pragma unroll
    for (int i = 0; i < 3; i++) {
        #pragma unroll
        for (int r = 0; r < 4; r++) {
            const int row = wid*48 + i*16 + g4*4 + r;
            const float pv = pinv[(size_t)b*NN + r0 + row] * SCALE;
            float l[3];
            float mx = -INFINITY;
            #pragma unroll
            for (int j = 0; j < 3; j++) {
                l[j] = acc[i][j][r] * pv + bias[j];
                mx = fmaxf(mx, l[j]);
            }
            #pragma unroll
            for (int m = 1; m <= 8; m <<= 1) mx = fmaxf(mx, __shfl_xor(mx, m, 64));
            float e[3], sum = 0.f;
            #pragma unroll
            for (int j = 0; j < 3; j++) { e[j] = expf(l[j] - mx); sum += e[j]; }
            #pragma unroll
            for (int m = 1; m <= 8; m <<= 1) sum += __shfl_xor(sum, m, 64);
            const float inv = 1.0f / sum;
            const size_t wbase = (size_t)(b*NN + r0 + row) * 64;
            #pragma unroll
            for (int j = 0; j < 3; j++) {
                const float wv = e[j] * inv;
                const f16 h = (f16)wv;
                w_hi[wbase + j*16 + q15] = h;
                w_lo[wbase + j*16 + q15] = (f16)(wv - (float)h);
            }
            // zero-pad K 48..63
            w_hi[wbase + 48 + q15] = (f16)0.f;
            w_lo[wbase + 48 + q15] = (f16)0.f;
        }
    }
}

// ---------------- kernel 4: queries = w @ T (MFMA, K=64 padded) -> q_hi/q_lo ----------------
// block: 128 n-rows x 128 d-cols, 4 waves (2x2, wave 64x64). grid (16 dt, 6 nt, 16 b).
__global__ __launch_bounds__(256) void k_qgen(const f16* __restrict__ w_hi,
                                              const f16* __restrict__ w_lo,
                                              const f16* __restrict__ t_hi,
                                              const f16* __restrict__ t_lo,
                                              f16* __restrict__ q_hi,
                                              f16* __restrict__ q_lo) {
    __shared__ f16 tth[128*72];
    __shared__ f16 ttl[128*72];
    const int d0 = blockIdx.x * 128;
    const int n0 = blockIdx.y * 128;
    const int b  = blockIdx.z;
    const int tid = threadIdx.x, wid = tid >> 6, lane = tid & 63;
    const int q15 = lane & 15, g4 = lane >> 4;
    const int wr = wid >> 1, wc = wid & 1;

    // build transposed task tiles: tth[d][t] = t_hi[b][t][d0+d]
    for (int u = tid; u < 48*128; u += 256) {
        const int t = u >> 7, c = u & 127;
        const size_t gi = ((size_t)(b*NT + t) << 11) + d0 + c;
        tth[c*72 + t] = t_hi[gi];
        ttl[c*72 + t] = t_lo[gi];
    }
    for (int u = tid; u < 128*16; u += 256) {
        const int c = u >> 4, t = 48 + (u & 15);
        tth[c*72 + t] = (f16)0.f;
        ttl[c*72 + t] = (f16)0.f;
    }
    __syncthreads();

    f32x4 acc[4][4];
    #pragma unroll
    for (int i = 0; i < 4; i++)
        #pragma unroll
        for (int j = 0; j < 4; j++) acc[i][j] = (f32x4){0.f,0.f,0.f,0.f};

    #pragma unroll
    for (int ksub = 0; ksub < 2; ksub++) {
        f16x8 ah[4], al[4], bh[4], bl[4];
        #pragma unroll
        for (int i = 0; i < 4; i++) {
            const size_t wb = (size_t)(b*NN + n0 + wr*64 + i*16 + q15)*64 + ksub*32 + g4*8;
            ah[i] = *(const f16x8*)&w_hi[wb];
            al[i] = *(const f16x8*)&w_lo[wb];
        }
        #pragma unroll
        for (int j = 0; j < 4; j++) {
            const int lb = (wc*64 + j*16 + q15)*72 + ksub*32 + g4*8;
            bh[j] = *(const f16x8*)&tth[lb];
            bl[j] = *(const f16x8*)&ttl[lb];
        }
        #pragma unroll
        for (int i = 0; i < 4; i++)
            #pragma unroll
            for (int j = 0; j < 4; j++) {
                acc[i][j] = __builtin_amdgcn_mfma_f32_16x16x32_f16(ah[i], bh[j], acc[i][j], 0, 0, 0);
                acc[i][j] = __builtin_amdgcn_mfma_f32_16x16x32_f16(al[i], bh[j], acc[i][j], 0, 0, 0);
                acc[i][j] = __builtin_amdgcn_mfma_f32_16x16x32_f16(ah[i], bl[j], acc[i][j], 0, 0, 0);
            }
    }

    // epilogue: split to hi/lo and store
    #pragma unroll
    for (int i = 0; i < 4; i++)
        #pragma unroll
        for (int r = 0; r < 4; r++) {
            const size_t qb = ((size_t)(b*NN + n0 + wr*64 + i*16 + g4*4 + r) << 11)
                              + d0 + wc*64 + q15;
            #pragma unroll
            for (int j = 0; j < 4; j++) {
                const float v = acc[i][j][r];
                const f16 h = (f16)v;
                q_hi[qb + j*16] = h;
                q_lo[qb + j*16] = (f16)(v - (float)h);
            }
        }
}

// ---------------- kernel 5: score MFMA (m97-style 128^2) + per-block top-2 ----------------
// tile 128x128, BK=64, 4 waves (2x2, wave 64x64), single-buffer 2-barrier loop.
// grid 6*6*16 = 576 blocks, XCD-chunked swizzle (576 % 8 == 0 -> bijective).
__global__ __launch_bounds__(256) void k_score3(
        const f16* __restrict__ q_hi, const f16* __restrict__ q_lo,
        const f16* __restrict__ p_hi, const f16* __restrict__ p_lo,
        const float* __restrict__ pinv, float4* __restrict__ part) {
    __shared__ __align__(16) char As[128*128];   // 16 KB
    __shared__ __align__(16) char Bs[128*128];
    __shared__ float4 red[2*128];
    const int tid = threadIdx.x, wid = tid >> 6, lane = tid & 63;
    const int q15 = lane & 15, g4 = lane >> 4;
    const int wr = wid >> 1, wc = wid & 1;
    const int lr = lane >> 3, lgch = (lane & 7) ^ lr;

    const int flat = blockIdx.x + 6*blockIdx.y + 36*blockIdx.z;
    const int logical = (flat & 7) * 72 + (flat >> 3);
    const int mt = logical % 6, rt = (logical / 6) % 6, b = logical / 36;

    const f16* gAh = q_hi + (size_t)(b*NN + rt*128) * ND;
    const f16* gAl = q_lo + (size_t)(b*NN + rt*128) * ND;
    const f16* gBh = p_hi + (size_t)(b*NN + mt*128) * ND;
    const f16* gBl = p_lo + (size_t)(b*NN + mt*128) * ND;

    f32x4 acc[4][4];
    #pragma unroll
    for (int i = 0; i < 4; i++)
        #pragma unroll
        for (int j = 0; j < 4; j++) acc[i][j] = (f32x4){0.f,0.f,0.f,0.f};

    const int cxor = q15 & 7;
    #pragma unroll 1
    for (int s = 0; s < 96; s++) {
        const int pass = s >> 5;
        const f16* gA = (pass == 1) ? gAl : gAh;
        const f16* gB = (pass == 2) ? gBl : gBh;
        const int kofs = (s & 31) * 64;
        #pragma unroll
        for (int ti = 0; ti < 4; ti++) {
            const int u = wid*4 + ti;
            const size_t go = (size_t)(u*8 + lr)*ND + kofs + lgch*8;
            stage16(gA + go, As + u*1024);
            stage16(gB + go, Bs + u*1024);
        }
        __syncthreads();
        #pragma unroll
        for (int ksub = 0; ksub < 2; ksub++) {
            const int chb = ((ksub*4 + g4) ^ cxor) << 4;
            f16x8 ah[4], bh[4];
            #pragma unroll
            for (int i = 0; i < 4; i++)
                ah[i] = *(const f16x8*)(As + (wr*64 + i*16 + q15)*128 + chb);
            #pragma unroll
            for (int j = 0; j < 4; j++)
                bh[j] = *(const f16x8*)(Bs + (wc*64 + j*16 + q15)*128 + chb);
            #pragma unroll
            for (int i = 0; i < 4; i++)
                #pragma unroll
                for (int j = 0; j < 4; j++)
                    acc[i][j] = __builtin_amdgcn_mfma_f32_16x16x32_f16(ah[i], bh[j], acc[i][j], 0, 0, 0);
        }
        __syncthreads();
    }

    // epilogue: scale by pinv[m], per-row top-2 (value desc, index asc)
    const int mbase = mt*128 + wc*64;
    float pv[4];
    #pragma unroll
    for (int j = 0; j < 4; j++) pv[j] = pinv[b*NN + mbase + j*16 + q15];
    #pragma unroll
    for (int i = 0; i < 4; i++) {
        #pragma unroll
        for (int r = 0; r < 4; r++) {
            float v1 = -INFINITY, v2 = -INFINITY; int i1 = 0;
            #pragma unroll
            for (int j = 0; j < 4; j++) {
                const float v = acc[i][j][r] * pv[j];
                const int m = mbase + j*16 + q15;
                if (v > v1) { v2 = v1; v1 = v; i1 = m; }
                else if (v > v2) v2 = v;
            }
            #pragma unroll
            for (int msk = 1; msk <= 8; msk <<= 1) {
                const float ov1 = __shfl_xor(v1, msk, 64);
                const int   oi1 = __shfl_xor(i1, msk, 64);
                const float ov2 = __shfl_xor(v2, msk, 64);
                if (ov1 > v1 || (ov1 == v1 && oi1 < i1)) { v2 = fmaxf(v1, ov2); v1 = ov1; i1 = oi1; }
                else v2 = fmaxf(v2, ov1);
            }
            if (q15 == 0)
                red[wc*128 + wr*64 + i*16 + g4*4 + r] = make_float4(v1, __int_as_float(i1), v2, 0.f);
        }
    }
    __syncthreads();
    if (tid < 128) {
        float4 e = red[tid];
        float4 f = red[128 + tid];
        float v1 = e.x, v2 = e.z; int i1 = __float_as_int(e.y);
        const int fi = __float_as_int(f.y);
        if (f.x > v1 || (f.x == v1 && fi < i1)) { v2 = fmaxf(v1, f.z); v1 = f.x; i1 = fi; }
        else v2 = fmaxf(v2, f.x);
        part[(size_t)(b*NN + rt*128 + tid)*6 + mt] = make_float4(v1, __int_as_float(i1), v2, 0.f);
    }
}

// ---------------- kernel 6: merge m-tiles -> idx + rescore flag ----------------
__global__ __launch_bounds__(256) void k_merge(const float4* __restrict__ part,
                                               int* __restrict__ idxarr,
                                               int* __restrict__ flags) {
    const int r = blockIdx.x * 256 + threadIdx.x;
    float4 e = part[(size_t)r*6];
    float v1 = e.x, v2 = e.z; int i1 = __float_as_int(e.y);
    #pragma unroll
    for (int t = 1; t < 6; t++) {
        float4 f = part[(size_t)r*6 + t];
        const int fi = __float_as_int(f.y);
        if (f.x > v1 || (f.x == v1 && fi < i1)) { v2 = fmaxf(v1, f.z); v1 = f.x; i1 = fi; }
        else v2 = fmaxf(v2, f.x);
    }
    idxarr[r] = i1;
    flags[r] = (v1 - v2 < TAU) ? 1 : 0;
}

// ---------------- kernel 7: exact fp32 rescore of ambiguous rows ----------------
__global__ __launch_bounds__(256) void k_rescore(const float* __restrict__ patches,
                                                 const f16* __restrict__ q_hi,
                                                 const f16* __restrict__ q_lo,
                                                 const float* __restrict__ pinv,
                                                 const int* __restrict__ flags,
                                                 int* __restrict__ idxarr) {
    const int row = blockIdx.x;
    if (!flags[row]) return;
    __shared__ float qrow[ND];
    __shared__ float sv[256];
    __shared__ int   si[256];
    const int b = row / NN;
    const int tid = threadIdx.x;
    const size_t qo = (size_t)row * ND;
    #pragma unroll
    for (int e = 0; e < 8; e++)
        qrow[tid*8 + e] = (float)q_hi[qo + tid*8 + e] + (float)q_lo[qo + tid*8 + e];
    __syncthreads();
    float bv = -INFINITY; int bm = 0;
    for (int mm = tid; mm < NN; mm += 256) {
        const float4* prow = (const float4*)(patches + ((size_t)b*NN + mm)*ND);
        float s = 0.f;
        for (int d4 = 0; d4 < ND/4; d4++) {
            float4 p = prow[d4];
            float4 qv = *(const float4*)&qrow[d4*4];
            s = fmaf(p.x, qv.x, s); s = fmaf(p.y, qv.y, s);
            s = fmaf(p.z, qv.z, s); s = fmaf(p.w, qv.w, s);
        }
        s *= pinv[(size_t)b*NN + mm];
        if (s > bv) { bv = s; bm = mm; }
    }
    sv[tid] = bv; si[tid] = bm;
    __syncthreads();
    for (int st = 128; st > 0; st >>= 1) {
        if (tid < st) {
            const float v = sv[tid+st]; const int m = si[tid+st];
            if (v > sv[tid] || (v == sv[tid] && m < si[tid])) { sv[tid] = v; si[tid] = m; }
        }
        __syncthreads();
    }
    if (tid == 0) idxarr[row] = si[0];
}

// ---------------- kernel 8: one-hot from idx ----------------
__global__ __launch_bounds__(256) void k_onehot_idx(const int* __restrict__ idxarr,
                                                    float* __restrict__ out) {
    const int g = blockIdx.x * 256 + threadIdx.x;      // float4 index
    const int row = g / (NN/4);
    const int j4  = g % (NN/4);
    const int m = idxarr[row];
    float4 o = {0.f, 0.f, 0.f, 0.f};
    if ((m >> 2) == j4) ((float*)&o)[m & 3] = 1.0f;
    ((float4*)out)[g] = o;
}

// ---------------- launcher ----------------
extern "C" void kernel_launch(void* const* d_in, const int* in_sizes, int n_in,
                              void* d_out, int out_size, void* d_ws, size_t ws_size,
                              hipStream_t stream) {
    const float* patches = (const float*)d_in[0];
    const float* task    = (const float*)d_in[1];
    const int*   mask    = (const int*)d_in[2];
    float* out = (float*)d_out;

    // workspace: pinv + 4 half arrays + idx + flags  (~201.6 MB, < proven 208.6)
    char* w = (char*)d_ws;
    float* pinv = (float*)w;              w += (size_t)NB*NN*sizeof(float);
    f16* p_hi = (f16*)w;                  w += (size_t)NB*NN*ND*sizeof(f16);
    f16* p_lo = (f16*)w;                  w += (size_t)NB*NN*ND*sizeof(f16);
    f16* q_hi = (f16*)w;                  w += (size_t)NB*NN*ND*sizeof(f16);
    f16* q_lo = (f16*)w;                  w += (size_t)NB*NN*ND*sizeof(f16);
    int* idxarr = (int*)w;                w += (size_t)NB*NN*sizeof(int);
    int* flags  = (int*)w;                w += (size_t)NB*NN*sizeof(int);

    // scratch inside d_out (fully overwritten by k_onehot_idx at the end)
    f16* t_hi = (f16*)out;                                  // 16*48*2048
    f16* t_lo = t_hi + (size_t)NB*NT*ND;
    f16* w_hi = t_lo + (size_t)NB*NT*ND;                    // 16*768*64
    f16* w_lo = w_hi + (size_t)NB*NN*64;
    float4* part = (float4*)(w_lo + (size_t)NB*NN*64);      // 12288 x 6

    k_prep_task<<<NB*NT, 256, 0, stream>>>(task, t_hi, t_lo);
    k_split_p<<<NB*NN, 256, 0, stream>>>(patches, pinv, p_hi, p_lo);
    k_logits<<<dim3(4, NB), 256, 0, stream>>>(p_hi, p_lo, t_hi, t_lo, pinv, mask, w_hi, w_lo);
    k_qgen<<<dim3(16, 6, NB), 256, 0, stream>>>(w_hi, w_lo, t_hi, t_lo, q_hi, q_lo);
    k_score3<<<dim3(6, 6, NB), 256, 0, stream>>>(q_hi, q_lo, p_hi, p_lo, pinv, part);
    k_merge<<<(NB*NN)/256, 256, 0, stream>>>(part, idxarr, flags);
    k_rescore<<<NB*NN, 256, 0, stream>>>(patches, q_hi, q_lo, pinv, flags, idxarr);
    k_onehot_idx<<<(NB*NN*NN/4)/256, 256, 0, stream>>>(idxarr, out);
}

// Round 5
// 304.797 us; speedup vs baseline: 1.1154x; 1.1154x over previous
//
#include <hip/hip_runtime.h>
#include <math.h>

#define NB 16
#define NN 768
#define NT 48
#define ND 2048
#define NROW (NB*NN)                 // 12288
#define SCALE 0.02209708691207961f   // 1/sqrt(2048)
#define NEGBIG (-3.4028234663852886e38f)
#define TAU 2e-3f
#define KS 512                        // K-slice per ks-block in k_R

typedef _Float16 f16;
typedef f16  f16x8 __attribute__((ext_vector_type(8)));
typedef f16  f16x4 __attribute__((ext_vector_type(4)));
typedef float f32x4 __attribute__((ext_vector_type(4)));

__device__ __forceinline__ void stage16(const void* g, void* l) {
    __builtin_amdgcn_global_load_lds(
        (const __attribute__((address_space(1))) unsigned int*)g,
        (__attribute__((address_space(3))) unsigned int*)l, 16, 0, 0);
}

// ---------------- kernel 1: task rms-norm -> task_n fp32 + t_hi/t_lo f16 ----------------
__global__ __launch_bounds__(256) void k_prep_task(const float* __restrict__ task,
                                                   float* __restrict__ task_n,
                                                   f16* __restrict__ t_hi,
                                                   f16* __restrict__ t_lo) {
    __shared__ float sred[8];
    const int row = blockIdx.x;                 // b*NT + t
    const float4* src = (const float4*)(task + (size_t)row * ND);
    const int tid = threadIdx.x;
    float4 v0 = src[tid];
    float4 v1 = src[tid + 256];
    float s = v0.x*v0.x + v0.y*v0.y + v0.z*v0.z + v0.w*v0.w
            + v1.x*v1.x + v1.y*v1.y + v1.z*v1.z + v1.w*v1.w;
    #pragma unroll
    for (int off = 32; off > 0; off >>= 1) s += __shfl_down(s, off, 64);
    if ((tid & 63) == 0) sred[tid >> 6] = s;
    __syncthreads();
    if (tid == 0)
        sred[4] = 1.0f / sqrtf((sred[0]+sred[1]+sred[2]+sred[3]) * (1.0f/ND) + 1e-6f);
    __syncthreads();
    const float inv = sred[4];
    const size_t o = (size_t)row * ND;
    f16x4 h0, l0, h1, l1;
    float4 n0, n1;
    #pragma unroll
    for (int e = 0; e < 4; e++) {
        float f0 = (&v0.x)[e] * inv, f1 = (&v1.x)[e] * inv;
        (&n0.x)[e] = f0; (&n1.x)[e] = f1;
        f16 a = (f16)f0; h0[e] = a; l0[e] = (f16)(f0 - (float)a);
        f16 c = (f16)f1; h1[e] = c; l1[e] = (f16)(f1 - (float)c);
    }
    *(float4*)&task_n[o + tid*4]          = n0;
    *(float4*)&task_n[o + (tid+256)*4]    = n1;
    *(f16x4*)&t_hi[o + tid*4]             = h0;
    *(f16x4*)&t_lo[o + tid*4]             = l0;
    *(f16x4*)&t_hi[o + (tid+256)*4]       = h1;
    *(f16x4*)&t_lo[o + (tid+256)*4]       = l1;
}

// ---------------- kernel 2: R-partials + sumsq-partials (streams patches ONCE) --------
// R[x,t] = P_raw[b,x] . T_n[b,t] over K-slice. block: 64 rows x KS, 4 waves.
// grid (12 rt, 4 ks, 16 b) = 768 blocks = 3/CU.
__global__ __launch_bounds__(256) void k_R(const float* __restrict__ patches,
                                           const f16* __restrict__ t_hi,
                                           const f16* __restrict__ t_lo,
                                           float* __restrict__ Rpart,
                                           float* __restrict__ ssqpart) {
    __shared__ __align__(16) char Ah[64*128], Al[64*128];   // 64 rows x 64 f16
    __shared__ __align__(16) char Bh[48*128], Bl[48*128];   // 48 rows x 64 f16
    const int rt = blockIdx.x, ks = blockIdx.y, b = blockIdx.z;
    const int tid = threadIdx.x, wid = tid >> 6, lane = tid & 63;
    const int q15 = lane & 15, g4 = lane >> 4;
    const int trow = tid >> 2, tq = tid & 3;   // A-load: row 0..63, quad pos
    const int lr = lane >> 3, lgch = (lane & 7) ^ lr;
    const int cxor = q15 & 7;

    const float* gP = patches + ((size_t)(b*NN + rt*64))*ND + ks*KS;
    const f16* gTh = t_hi + (size_t)b*NT*ND + ks*KS;
    const f16* gTl = t_lo + (size_t)b*NT*ND + ks*KS;

    f32x4 acc[3];
    #pragma unroll
    for (int j = 0; j < 3; j++) acc[j] = (f32x4){0.f,0.f,0.f,0.f};
    float ssq = 0.f;

    for (int kk = 0; kk < KS; kk += 64) {
        // stage B (tiny, L2-hot) via gload_lds with pre-swizzled source
        #pragma unroll
        for (int t2 = 0; t2 < 2; t2++) {
            const int u = wid + 4*t2;
            if (u < 6) {
                stage16(gTh + (size_t)(u*8 + lr)*ND + kk + lgch*8, Bh + u*1024);
                stage16(gTl + (size_t)(u*8 + lr)*ND + kk + lgch*8, Bl + u*1024);
            }
        }
        // A: 64B contiguous fp32 per thread -> sumsq + f16 hi/lo split -> swizzled LDS
        float4 v[4];
        #pragma unroll
        for (int k = 0; k < 4; k++)
            v[k] = *(const float4*)(gP + (size_t)trow*ND + kk + tq*16 + k*4);
        float lssq = 0.f;
        f16x8 hi8[2], lo8[2];
        #pragma unroll
        for (int k = 0; k < 4; k++)
            #pragma unroll
            for (int e = 0; e < 4; e++) {
                const float f = (&v[k].x)[e];
                lssq += f*f;
                const f16 h = (f16)f;
                hi8[k>>1][(k&1)*4 + e] = h;
                lo8[k>>1][(k&1)*4 + e] = (f16)(f - (float)h);
            }
        lssq += __shfl_xor(lssq, 1, 64);
        lssq += __shfl_xor(lssq, 2, 64);
        if (tq == 0) ssq += lssq;
        const int rb = trow * 128;
        #pragma unroll
        for (int c = 0; c < 2; c++) {
            const int ch = (2*tq + c) ^ (trow & 7);
            *(f16x8*)(Ah + rb + ch*16) = hi8[c];
            *(f16x8*)(Al + rb + ch*16) = lo8[c];
        }
        __syncthreads();
        // MFMA: wave wid owns A-rows wid*16..+15, 3 col tiles, 3-pass hi/lo
        #pragma unroll
        for (int ksub = 0; ksub < 2; ksub++) {
            const int chb = ((ksub*4 + g4) ^ cxor) << 4;
            const f16x8 a_h = *(const f16x8*)(Ah + (wid*16 + q15)*128 + chb);
            const f16x8 a_l = *(const f16x8*)(Al + (wid*16 + q15)*128 + chb);
            #pragma unroll
            for (int j = 0; j < 3; j++) {
                const f16x8 b_h = *(const f16x8*)(Bh + (j*16 + q15)*128 + chb);
                const f16x8 b_l = *(const f16x8*)(Bl + (j*16 + q15)*128 + chb);
                acc[j] = __builtin_amdgcn_mfma_f32_16x16x32_f16(a_h, b_h, acc[j], 0, 0, 0);
                acc[j] = __builtin_amdgcn_mfma_f32_16x16x32_f16(a_l, b_h, acc[j], 0, 0, 0);
                acc[j] = __builtin_amdgcn_mfma_f32_16x16x32_f16(a_h, b_l, acc[j], 0, 0, 0);
            }
        }
        __syncthreads();
    }
    const int grow = b*NN + rt*64;
    #pragma unroll
    for (int j = 0; j < 3; j++)
        #pragma unroll
        for (int r = 0; r < 4; r++)
            Rpart[((size_t)ks*NROW + grow + wid*16 + g4*4 + r)*48 + j*16 + q15] = acc[j][r];
    if (tq == 0)
        ssqpart[(size_t)ks*NROW + grow + trow] = ssq;
}

// ---------------- kernel 3: combine partials -> pinv, R, w(softmax) ----------------
__global__ __launch_bounds__(256) void k_combine(const float* __restrict__ Rpart,
                                                 const float* __restrict__ ssqpart,
                                                 const int* __restrict__ mask,
                                                 float* __restrict__ R,
                                                 float* __restrict__ w,
                                                 float* __restrict__ pinv) {
    const int r = blockIdx.x * 256 + threadIdx.x;   // 0..12287
    const int b = r / NN;
    float ss = 0.f;
    #pragma unroll
    for (int ks = 0; ks < 4; ks++) ss += ssqpart[(size_t)ks*NROW + r];
    const float pv = 1.0f / sqrtf(ss * (1.0f/ND) + 1e-6f);
    pinv[r] = pv;
    float l[48];
    float mx = -INFINITY;
    #pragma unroll
    for (int t4 = 0; t4 < 12; t4++) {
        float4 a = {0.f,0.f,0.f,0.f};
        #pragma unroll
        for (int ks = 0; ks < 4; ks++) {
            const float4 p = *(const float4*)&Rpart[((size_t)ks*NROW + r)*48 + t4*4];
            a.x += p.x; a.y += p.y; a.z += p.z; a.w += p.w;
        }
        *(float4*)&R[(size_t)r*48 + t4*4] = a;
        #pragma unroll
        for (int e = 0; e < 4; e++) {
            const int t = t4*4 + e;
            const float bias = mask[b*NT + t] ? 0.0f : NEGBIG;
            l[t] = (&a.x)[e] * pv * SCALE + bias;
            mx = fmaxf(mx, l[t]);
        }
    }
    float sum = 0.f;
    #pragma unroll
    for (int t = 0; t < 48; t++) { l[t] = expf(l[t] - mx); sum += l[t]; }
    const float inv = 1.0f / sum;
    #pragma unroll
    for (int t4 = 0; t4 < 12; t4++) {
        float4 o;
        #pragma unroll
        for (int e = 0; e < 4; e++) (&o.x)[e] = l[t4*4 + e] * inv;
        *(float4*)&w[(size_t)r*48 + t4*4] = o;
    }
}

// ---------------- kernel 4: score = pinv[m] * (W . R^T), fused top-2 ----------------
// block: 256 rows x 96 m, K=48. grid (48 rt, 8 ms) = 384 blocks.
__global__ __launch_bounds__(256) void k_scoreW(const float* __restrict__ w,
                                                const float* __restrict__ R,
                                                const float* __restrict__ pinv,
                                                float4* __restrict__ part) {
    __shared__ float Rl[96*48];
    __shared__ float pl[96];
    const int rt = blockIdx.x, ms = blockIdx.y;
    const int tid = threadIdx.x;
    const int row = rt*256 + tid;
    const int b = row / NN;                 // constant per block (256 | 768)
    const int m0g = b*NN + ms*96;
    for (int u = tid; u < 96*12; u += 256) {
        const int m = u / 12, t4 = u % 12;
        *(float4*)&Rl[m*48 + t4*4] = *(const float4*)&R[((size_t)(m0g + m))*48 + t4*4];
    }
    if (tid < 96) pl[tid] = pinv[m0g + tid];
    __syncthreads();
    float4 wr[12];
    #pragma unroll
    for (int t4 = 0; t4 < 12; t4++)
        wr[t4] = *(const float4*)&w[(size_t)row*48 + t4*4];
    float v1 = -INFINITY, v2 = -INFINITY; int i1 = 0;
    for (int m = 0; m < 96; m++) {
        float s = 0.f;
        #pragma unroll
        for (int t4 = 0; t4 < 12; t4++) {
            const float4 rv = *(const float4*)&Rl[m*48 + t4*4];   // broadcast
            s = fmaf(wr[t4].x, rv.x, s); s = fmaf(wr[t4].y, rv.y, s);
            s = fmaf(wr[t4].z, rv.z, s); s = fmaf(wr[t4].w, rv.w, s);
        }
        s *= pl[m];
        if (s > v1) { v2 = v1; v1 = s; i1 = ms*96 + m; }
        else if (s > v2) v2 = s;
    }
    part[(size_t)row*8 + ms] = make_float4(v1, __int_as_float(i1), v2, 0.f);
}

// ---------------- kernel 5: merge 8 m-chunks -> idx + rescore flag ----------------
__global__ __launch_bounds__(256) void k_merge(const float4* __restrict__ part,
                                               int* __restrict__ idxarr,
                                               int* __restrict__ flags) {
    const int r = blockIdx.x * 256 + threadIdx.x;
    float4 e = part[(size_t)r*8];
    float v1 = e.x, v2 = e.z; int i1 = __float_as_int(e.y);
    #pragma unroll
    for (int t = 1; t < 8; t++) {
        const float4 f = part[(size_t)r*8 + t];
        const int fi = __float_as_int(f.y);
        if (f.x > v1 || (f.x == v1 && fi < i1)) { v2 = fmaxf(v1, f.z); v1 = f.x; i1 = fi; }
        else v2 = fmaxf(v2, f.x);
    }
    idxarr[r] = i1;
    flags[r] = (v1 - v2 < TAU) ? 1 : 0;
}

// ---------------- kernel 6: exact fp32 rescore of ambiguous rows ----------------
__global__ __launch_bounds__(256) void k_rescore(const float* __restrict__ patches,
                                                 const float* __restrict__ task_n,
                                                 const float* __restrict__ w,
                                                 const float* __restrict__ pinv,
                                                 const int* __restrict__ flags,
                                                 int* __restrict__ idxarr) {
    const int row = blockIdx.x;
    if (!flags[row]) return;
    __shared__ float wl[48];
    __shared__ float qrow[ND];
    __shared__ float sv[256];
    __shared__ int   si[256];
    const int b = row / NN;
    const int tid = threadIdx.x;
    if (tid < 12) *(float4*)&wl[tid*4] = *(const float4*)&w[(size_t)row*48 + tid*4];
    __syncthreads();
    float q[8] = {0.f,0.f,0.f,0.f,0.f,0.f,0.f,0.f};
    for (int t = 0; t < NT; t++) {
        const float wt = wl[t];
        const float* Tn = task_n + ((size_t)(b*NT + t))*ND + tid*8;
        const float4 u0 = *(const float4*)Tn;
        const float4 u1 = *(const float4*)(Tn + 4);
        q[0] = fmaf(wt, u0.x, q[0]); q[1] = fmaf(wt, u0.y, q[1]);
        q[2] = fmaf(wt, u0.z, q[2]); q[3] = fmaf(wt, u0.w, q[3]);
        q[4] = fmaf(wt, u1.x, q[4]); q[5] = fmaf(wt, u1.y, q[5]);
        q[6] = fmaf(wt, u1.z, q[6]); q[7] = fmaf(wt, u1.w, q[7]);
    }
    #pragma unroll
    for (int e = 0; e < 8; e++) qrow[tid*8 + e] = q[e];
    __syncthreads();
    float bv = -INFINITY; int bm = 0;
    for (int mm = tid; mm < NN; mm += 256) {
        const float4* prow = (const float4*)(patches + ((size_t)b*NN + mm)*ND);
        float s = 0.f;
        for (int d4 = 0; d4 < ND/4; d4++) {
            const float4 p = prow[d4];
            const float4 qv = *(const float4*)&qrow[d4*4];
            s = fmaf(p.x, qv.x, s); s = fmaf(p.y, qv.y, s);
            s = fmaf(p.z, qv.z, s); s = fmaf(p.w, qv.w, s);
        }
        s *= pinv[(size_t)b*NN + mm];
        if (s > bv) { bv = s; bm = mm; }
    }
    sv[tid] = bv; si[tid] = bm;
    __syncthreads();
    for (int st = 128; st > 0; st >>= 1) {
        if (tid < st) {
            const float v = sv[tid+st]; const int m = si[tid+st];
            if (v > sv[tid] || (v == sv[tid] && m < si[tid])) { sv[tid] = v; si[tid] = m; }
        }
        __syncthreads();
    }
    if (tid == 0) idxarr[row] = si[0];
}

// ---------------- kernel 7: one-hot from idx ----------------
__global__ __launch_bounds__(256) void k_onehot_idx(const int* __restrict__ idxarr,
                                                    float* __restrict__ out) {
    const int g = blockIdx.x * 256 + threadIdx.x;      // float4 index
    const int row = g / (NN/4);
    const int j4  = g % (NN/4);
    const int m = idxarr[row];
    float4 o = {0.f, 0.f, 0.f, 0.f};
    if ((m >> 2) == j4) ((float*)&o)[m & 3] = 1.0f;
    ((float4*)out)[g] = o;
}

// ---------------- launcher ----------------
extern "C" void kernel_launch(void* const* d_in, const int* in_sizes, int n_in,
                              void* d_out, int out_size, void* d_ws, size_t ws_size,
                              hipStream_t stream) {
    const float* patches = (const float*)d_in[0];
    const float* task    = (const float*)d_in[1];
    const int*   mask    = (const int*)d_in[2];
    float* out = (float*)d_out;

    // workspace (~25.6 MB total)
    char* p = (char*)d_ws;
    float* task_n  = (float*)p;  p += (size_t)NB*NT*ND*sizeof(float);    // 6.29 MB
    f16*   t_hi    = (f16*)p;    p += (size_t)NB*NT*ND*sizeof(f16);      // 3.15 MB
    f16*   t_lo    = (f16*)p;    p += (size_t)NB*NT*ND*sizeof(f16);      // 3.15 MB
    float* Rpart   = (float*)p;  p += (size_t)4*NROW*48*sizeof(float);   // 9.44 MB
    float* ssqpart = (float*)p;  p += (size_t)4*NROW*sizeof(float);      // 197 KB
    float* R       = (float*)p;  p += (size_t)NROW*48*sizeof(float);     // 2.36 MB
    float* w       = (float*)p;  p += (size_t)NROW*48*sizeof(float);     // 2.36 MB
    float* pinv    = (float*)p;  p += (size_t)NROW*sizeof(float);        // 49 KB
    float4* part   = (float4*)p; p += (size_t)NROW*8*sizeof(float4);     // 1.57 MB
    int*   idxarr  = (int*)p;    p += (size_t)NROW*sizeof(int);
    int*   flags   = (int*)p;    p += (size_t)NROW*sizeof(int);

    k_prep_task<<<NB*NT, 256, 0, stream>>>(task, task_n, t_hi, t_lo);
    k_R<<<dim3(NN/64, 4, NB), 256, 0, stream>>>(patches, t_hi, t_lo, Rpart, ssqpart);
    k_combine<<<NROW/256, 256, 0, stream>>>(Rpart, ssqpart, mask, R, w, pinv);
    k_scoreW<<<dim3(NROW/256, 8), 256, 0, stream>>>(w, R, pinv, part);
    k_merge<<<NROW/256, 256, 0, stream>>>(part, idxarr, flags);
    k_rescore<<<NROW, 256, 0, stream>>>(patches, task_n, w, pinv, flags, idxarr);
    k_onehot_idx<<<(NROW*(NN/4))/256, 256, 0, stream>>>(idxarr, out);
}

// Round 6
// 144.933 us; speedup vs baseline: 2.3456x; 2.1030x over previous
//
#include <hip/hip_runtime.h>
#include <math.h>

#define NB 16
#define NN 768
#define NT 48
#define ND 2048
#define NROW (NB*NN)                 // 12288
#define SCALE 0.02209708691207961f   // 1/sqrt(2048)
#define NEGBIG (-3.4028234663852886e38f)
#define TAU 2e-3f
#define KS 512                        // K-slice per ks-block in k_R

typedef _Float16 f16;
typedef f16  f16x8 __attribute__((ext_vector_type(8)));
typedef f16  f16x4 __attribute__((ext_vector_type(4)));
typedef float f32x4 __attribute__((ext_vector_type(4)));

__device__ __forceinline__ void stage16(const void* g, void* l) {
    __builtin_amdgcn_global_load_lds(
        (const __attribute__((address_space(1))) unsigned int*)g,
        (__attribute__((address_space(3))) unsigned int*)l, 16, 0, 0);
}

// branchless sorted-desc top-4 insert (value desc, index asc tie-break).
// all array accesses static after unroll (rule #20 safe).
__device__ __forceinline__ void ins4(float v[4], int idx[4], float nv, int ni) {
    const bool b0 = (v[0] > nv) || (v[0] == nv && idx[0] < ni);
    const bool b1 = (v[1] > nv) || (v[1] == nv && idx[1] < ni);
    const bool b2 = (v[2] > nv) || (v[2] == nv && idx[2] < ni);
    const bool b3 = (v[3] > nv) || (v[3] == nv && idx[3] < ni);
    const int pos = (int)b0 + (int)b1 + (int)b2 + (int)b3;
    if (pos <= 3) { if (pos == 3) { v[3] = nv; idx[3] = ni; } else { v[3] = v[2]; idx[3] = idx[2]; } }
    if (pos <= 2) { if (pos == 2) { v[2] = nv; idx[2] = ni; } else { v[2] = v[1]; idx[2] = idx[1]; } }
    if (pos <= 1) { if (pos == 1) { v[1] = nv; idx[1] = ni; } else { v[1] = v[0]; idx[1] = idx[0]; } }
    if (pos == 0) { v[0] = nv; idx[0] = ni; }
}

// ---------------- kernel 1: task rms-norm -> task_n fp32 + t_hi/t_lo f16 ----------------
__global__ __launch_bounds__(256) void k_prep_task(const float* __restrict__ task,
                                                   float* __restrict__ task_n,
                                                   f16* __restrict__ t_hi,
                                                   f16* __restrict__ t_lo) {
    __shared__ float sred[8];
    const int row = blockIdx.x;                 // b*NT + t
    const float4* src = (const float4*)(task + (size_t)row * ND);
    const int tid = threadIdx.x;
    float4 v0 = src[tid];
    float4 v1 = src[tid + 256];
    float s = v0.x*v0.x + v0.y*v0.y + v0.z*v0.z + v0.w*v0.w
            + v1.x*v1.x + v1.y*v1.y + v1.z*v1.z + v1.w*v1.w;
    #pragma unroll
    for (int off = 32; off > 0; off >>= 1) s += __shfl_down(s, off, 64);
    if ((tid & 63) == 0) sred[tid >> 6] = s;
    __syncthreads();
    if (tid == 0)
        sred[4] = 1.0f / sqrtf((sred[0]+sred[1]+sred[2]+sred[3]) * (1.0f/ND) + 1e-6f);
    __syncthreads();
    const float inv = sred[4];
    const size_t o = (size_t)row * ND;
    f16x4 h0, l0, h1, l1;
    float4 n0, n1;
    #pragma unroll
    for (int e = 0; e < 4; e++) {
        float f0 = (&v0.x)[e] * inv, f1 = (&v1.x)[e] * inv;
        (&n0.x)[e] = f0; (&n1.x)[e] = f1;
        f16 a = (f16)f0; h0[e] = a; l0[e] = (f16)(f0 - (float)a);
        f16 c = (f16)f1; h1[e] = c; l1[e] = (f16)(f1 - (float)c);
    }
    *(float4*)&task_n[o + tid*4]          = n0;
    *(float4*)&task_n[o + (tid+256)*4]    = n1;
    *(f16x4*)&t_hi[o + tid*4]             = h0;
    *(f16x4*)&t_lo[o + tid*4]             = l0;
    *(f16x4*)&t_hi[o + (tid+256)*4]       = h1;
    *(f16x4*)&t_lo[o + (tid+256)*4]       = l1;
}

// ---------------- kernel 2: R-partials + sumsq-partials (streams patches ONCE) --------
__global__ __launch_bounds__(256) void k_R(const float* __restrict__ patches,
                                           const f16* __restrict__ t_hi,
                                           const f16* __restrict__ t_lo,
                                           float* __restrict__ Rpart,
                                           float* __restrict__ ssqpart) {
    __shared__ __align__(16) char Ah[64*128], Al[64*128];   // 64 rows x 64 f16
    __shared__ __align__(16) char Bh[48*128], Bl[48*128];   // 48 rows x 64 f16
    const int rt = blockIdx.x, ks = blockIdx.y, b = blockIdx.z;
    const int tid = threadIdx.x, wid = tid >> 6, lane = tid & 63;
    const int q15 = lane & 15, g4 = lane >> 4;
    const int trow = tid >> 2, tq = tid & 3;   // A-load: row 0..63, quad pos
    const int lr = lane >> 3, lgch = (lane & 7) ^ lr;
    const int cxor = q15 & 7;

    const float* gP = patches + ((size_t)(b*NN + rt*64))*ND + ks*KS;
    const f16* gTh = t_hi + (size_t)b*NT*ND + ks*KS;
    const f16* gTl = t_lo + (size_t)b*NT*ND + ks*KS;

    f32x4 acc[3];
    #pragma unroll
    for (int j = 0; j < 3; j++) acc[j] = (f32x4){0.f,0.f,0.f,0.f};
    float ssq = 0.f;

    for (int kk = 0; kk < KS; kk += 64) {
        #pragma unroll
        for (int t2 = 0; t2 < 2; t2++) {
            const int u = wid + 4*t2;
            if (u < 6) {
                stage16(gTh + (size_t)(u*8 + lr)*ND + kk + lgch*8, Bh + u*1024);
                stage16(gTl + (size_t)(u*8 + lr)*ND + kk + lgch*8, Bl + u*1024);
            }
        }
        float4 v[4];
        #pragma unroll
        for (int k = 0; k < 4; k++)
            v[k] = *(const float4*)(gP + (size_t)trow*ND + kk + tq*16 + k*4);
        float lssq = 0.f;
        f16x8 hi8[2], lo8[2];
        #pragma unroll
        for (int k = 0; k < 4; k++)
            #pragma unroll
            for (int e = 0; e < 4; e++) {
                const float f = (&v[k].x)[e];
                lssq += f*f;
                const f16 h = (f16)f;
                hi8[k>>1][(k&1)*4 + e] = h;
                lo8[k>>1][(k&1)*4 + e] = (f16)(f - (float)h);
            }
        lssq += __shfl_xor(lssq, 1, 64);
        lssq += __shfl_xor(lssq, 2, 64);
        if (tq == 0) ssq += lssq;
        const int rb = trow * 128;
        #pragma unroll
        for (int c = 0; c < 2; c++) {
            const int ch = (2*tq + c) ^ (trow & 7);
            *(f16x8*)(Ah + rb + ch*16) = hi8[c];
            *(f16x8*)(Al + rb + ch*16) = lo8[c];
        }
        __syncthreads();
        #pragma unroll
        for (int ksub = 0; ksub < 2; ksub++) {
            const int chb = ((ksub*4 + g4) ^ cxor) << 4;
            const f16x8 a_h = *(const f16x8*)(Ah + (wid*16 + q15)*128 + chb);
            const f16x8 a_l = *(const f16x8*)(Al + (wid*16 + q15)*128 + chb);
            #pragma unroll
            for (int j = 0; j < 3; j++) {
                const f16x8 b_h = *(const f16x8*)(Bh + (j*16 + q15)*128 + chb);
                const f16x8 b_l = *(const f16x8*)(Bl + (j*16 + q15)*128 + chb);
                acc[j] = __builtin_amdgcn_mfma_f32_16x16x32_f16(a_h, b_h, acc[j], 0, 0, 0);
                acc[j] = __builtin_amdgcn_mfma_f32_16x16x32_f16(a_l, b_h, acc[j], 0, 0, 0);
                acc[j] = __builtin_amdgcn_mfma_f32_16x16x32_f16(a_h, b_l, acc[j], 0, 0, 0);
            }
        }
        __syncthreads();
    }
    const int grow = b*NN + rt*64;
    #pragma unroll
    for (int j = 0; j < 3; j++)
        #pragma unroll
        for (int r = 0; r < 4; r++)
            Rpart[((size_t)ks*NROW + grow + wid*16 + g4*4 + r)*48 + j*16 + q15] = acc[j][r];
    if (tq == 0)
        ssqpart[(size_t)ks*NROW + grow + trow] = ssq;
}

// ---------------- kernel 3: combine partials -> pinv, R, w(softmax) ----------------
__global__ __launch_bounds__(256) void k_combine(const float* __restrict__ Rpart,
                                                 const float* __restrict__ ssqpart,
                                                 const int* __restrict__ mask,
                                                 float* __restrict__ R,
                                                 float* __restrict__ w,
                                                 float* __restrict__ pinv) {
    const int r = blockIdx.x * 256 + threadIdx.x;   // 0..12287
    const int b = r / NN;
    float ss = 0.f;
    #pragma unroll
    for (int ks = 0; ks < 4; ks++) ss += ssqpart[(size_t)ks*NROW + r];
    const float pv = 1.0f / sqrtf(ss * (1.0f/ND) + 1e-6f);
    pinv[r] = pv;
    float l[48];
    float mx = -INFINITY;
    #pragma unroll
    for (int t4 = 0; t4 < 12; t4++) {
        float4 a = {0.f,0.f,0.f,0.f};
        #pragma unroll
        for (int ks = 0; ks < 4; ks++) {
            const float4 p = *(const float4*)&Rpart[((size_t)ks*NROW + r)*48 + t4*4];
            a.x += p.x; a.y += p.y; a.z += p.z; a.w += p.w;
        }
        *(float4*)&R[(size_t)r*48 + t4*4] = a;
        #pragma unroll
        for (int e = 0; e < 4; e++) {
            const int t = t4*4 + e;
            const float bias = mask[b*NT + t] ? 0.0f : NEGBIG;
            l[t] = (&a.x)[e] * pv * SCALE + bias;
            mx = fmaxf(mx, l[t]);
        }
    }
    float sum = 0.f;
    #pragma unroll
    for (int t = 0; t < 48; t++) { l[t] = expf(l[t] - mx); sum += l[t]; }
    const float inv = 1.0f / sum;
    #pragma unroll
    for (int t4 = 0; t4 < 12; t4++) {
        float4 o;
        #pragma unroll
        for (int e = 0; e < 4; e++) (&o.x)[e] = l[t4*4 + e] * inv;
        *(float4*)&w[(size_t)r*48 + t4*4] = o;
    }
}

// ---------------- kernel 4: score = pinv[m]*(W.R^T), per-chunk TOP-4 ----------------
// block: 256 rows x 96 m, K=48. grid (48 rt, 8 ms) = 384 blocks.
// part layout: 2 float4 per (row, ms): {v1,i1,v2,i2},{v3,i3,v4,i4}
__global__ __launch_bounds__(256) void k_scoreW(const float* __restrict__ w,
                                                const float* __restrict__ R,
                                                const float* __restrict__ pinv,
                                                float4* __restrict__ part) {
    __shared__ float Rl[96*48];
    __shared__ float pl[96];
    const int rt = blockIdx.x, ms = blockIdx.y;
    const int tid = threadIdx.x;
    const int row = rt*256 + tid;
    const int b = row / NN;                 // constant per block (256 | 768)
    const int m0g = b*NN + ms*96;
    for (int u = tid; u < 96*12; u += 256) {
        const int m = u / 12, t4 = u % 12;
        *(float4*)&Rl[m*48 + t4*4] = *(const float4*)&R[((size_t)(m0g + m))*48 + t4*4];
    }
    if (tid < 96) pl[tid] = pinv[m0g + tid];
    __syncthreads();
    float4 wr[12];
    #pragma unroll
    for (int t4 = 0; t4 < 12; t4++)
        wr[t4] = *(const float4*)&w[(size_t)row*48 + t4*4];
    float tv[4] = {-INFINITY, -INFINITY, -INFINITY, -INFINITY};
    int   ti[4] = {0x7FFFFFFF, 0x7FFFFFFF, 0x7FFFFFFF, 0x7FFFFFFF};
    for (int m = 0; m < 96; m++) {
        float s = 0.f;
        #pragma unroll
        for (int t4 = 0; t4 < 12; t4++) {
            const float4 rv = *(const float4*)&Rl[m*48 + t4*4];   // broadcast
            s = fmaf(wr[t4].x, rv.x, s); s = fmaf(wr[t4].y, rv.y, s);
            s = fmaf(wr[t4].z, rv.z, s); s = fmaf(wr[t4].w, rv.w, s);
        }
        s *= pl[m];
        ins4(tv, ti, s, ms*96 + m);
    }
    part[((size_t)row*8 + ms)*2]     = make_float4(tv[0], __int_as_float(ti[0]), tv[1], __int_as_float(ti[1]));
    part[((size_t)row*8 + ms)*2 + 1] = make_float4(tv[2], __int_as_float(ti[2]), tv[3], __int_as_float(ti[3]));
}

// ---------------- kernel 5: merge 8 chunks' top-4 -> global top-4, flags, cand ------
__global__ __launch_bounds__(256) void k_merge(const float4* __restrict__ part,
                                               int* __restrict__ idxarr,
                                               int* __restrict__ flags,
                                               int4* __restrict__ cand) {
    const int r = blockIdx.x * 256 + threadIdx.x;
    float tv[4] = {-INFINITY, -INFINITY, -INFINITY, -INFINITY};
    int   ti[4] = {0x7FFFFFFF, 0x7FFFFFFF, 0x7FFFFFFF, 0x7FFFFFFF};
    #pragma unroll
    for (int t = 0; t < 8; t++) {
        const float4 e0 = part[((size_t)r*8 + t)*2];
        const float4 e1 = part[((size_t)r*8 + t)*2 + 1];
        ins4(tv, ti, e0.x, __float_as_int(e0.y));
        ins4(tv, ti, e0.z, __float_as_int(e0.w));
        ins4(tv, ti, e1.x, __float_as_int(e1.y));
        ins4(tv, ti, e1.z, __float_as_int(e1.w));
    }
    idxarr[r] = ti[0];
    int fl = 0;
    if (tv[0] - tv[1] < TAU) fl = 1;
    if (tv[0] - tv[3] < TAU) fl = 2;       // pathological: need full scan
    flags[r] = fl;
    if (fl) cand[r] = make_int4(ti[0], ti[1], ti[2], ti[3]);
}

// ---------------- kernel 6: exact fp32 rescore (wave-parallel, candidates only) -----
__global__ __launch_bounds__(256) void k_rescore(const float* __restrict__ patches,
                                                 const float* __restrict__ task_n,
                                                 const float* __restrict__ w,
                                                 const float* __restrict__ pinv,
                                                 const int* __restrict__ flags,
                                                 const int4* __restrict__ cand,
                                                 int* __restrict__ idxarr) {
    const int row = blockIdx.x;
    const int fl = flags[row];
    if (!fl) return;
    __shared__ float wl[48];
    __shared__ float qrow[ND];
    __shared__ float sv[4];
    __shared__ int   si[4];
    __shared__ int   sc[4];
    const int b = row / NN;
    const int tid = threadIdx.x, wid = tid >> 6, lane = tid & 63;
    if (tid < 12) *(float4*)&wl[tid*4] = *(const float4*)&w[(size_t)row*48 + tid*4];
    if (tid < 4) {
        const int4 c4 = cand[row];
        sc[tid] = (tid == 0) ? c4.x : (tid == 1) ? c4.y : (tid == 2) ? c4.z : c4.w;
    }
    __syncthreads();
    // q = w . task_n  (exact fp32), cooperative
    {
        float q[8] = {0.f,0.f,0.f,0.f,0.f,0.f,0.f,0.f};
        for (int t = 0; t < NT; t++) {
            const float wt = wl[t];
            const float* Tn = task_n + ((size_t)(b*NT + t))*ND + tid*8;
            const float4 u0 = *(const float4*)Tn;
            const float4 u1 = *(const float4*)(Tn + 4);
            q[0] = fmaf(wt, u0.x, q[0]); q[1] = fmaf(wt, u0.y, q[1]);
            q[2] = fmaf(wt, u0.z, q[2]); q[3] = fmaf(wt, u0.w, q[3]);
            q[4] = fmaf(wt, u1.x, q[4]); q[5] = fmaf(wt, u1.y, q[5]);
            q[6] = fmaf(wt, u1.z, q[6]); q[7] = fmaf(wt, u1.w, q[7]);
        }
        #pragma unroll
        for (int e = 0; e < 8; e++) qrow[tid*8 + e] = q[e];
    }
    __syncthreads();

    if (fl == 1) {
        // wave wid rescores candidate sc[wid]: lane-parallel dot over 2048
        const int c = sc[wid];
        const float* prow = patches + ((size_t)b*NN + c)*ND + lane*32;
        const float* qp = qrow + lane*32;
        float s = 0.f;
        #pragma unroll
        for (int k = 0; k < 8; k++) {
            const float4 p = *(const float4*)(prow + k*4);
            const float4 qv = *(const float4*)(qp + k*4);
            s = fmaf(p.x, qv.x, s); s = fmaf(p.y, qv.y, s);
            s = fmaf(p.z, qv.z, s); s = fmaf(p.w, qv.w, s);
        }
        #pragma unroll
        for (int off = 32; off > 0; off >>= 1) s += __shfl_down(s, off, 64);
        if (lane == 0) { sv[wid] = s * pinv[b*NN + c]; si[wid] = c; }
        __syncthreads();
        if (tid == 0) {
            float bv = sv[0]; int bm = si[0];
            #pragma unroll
            for (int k = 1; k < 4; k++) {
                if (sv[k] > bv || (sv[k] == bv && si[k] < bm)) { bv = sv[k]; bm = si[k]; }
            }
            idxarr[row] = bm;
        }
    } else {
        // full scan: wave wid handles m = wid, wid+4, ...
        float bv = -INFINITY; int bm = 0;
        for (int m = wid; m < NN; m += 4) {
            const float* prow = patches + ((size_t)b*NN + m)*ND + lane*32;
            const float* qp = qrow + lane*32;
            float s = 0.f;
            #pragma unroll
            for (int k = 0; k < 8; k++) {
                const float4 p = *(const float4*)(prow + k*4);
                const float4 qv = *(const float4*)(qp + k*4);
                s = fmaf(p.x, qv.x, s); s = fmaf(p.y, qv.y, s);
                s = fmaf(p.z, qv.z, s); s = fmaf(p.w, qv.w, s);
            }
            #pragma unroll
            for (int off = 32; off > 0; off >>= 1) s += __shfl_down(s, off, 64);
            if (lane == 0) {
                s *= pinv[b*NN + m];
                if (s > bv) { bv = s; bm = m; }
            }
        }
        if (lane == 0) { sv[wid] = bv; si[wid] = bm; }
        __syncthreads();
        if (tid == 0) {
            float v = sv[0]; int bi = si[0];
            #pragma unroll
            for (int k = 1; k < 4; k++) {
                if (sv[k] > v || (sv[k] == v && si[k] < bi)) { v = sv[k]; bi = si[k]; }
            }
            idxarr[row] = bi;
        }
    }
}

// ---------------- kernel 7: one-hot from idx ----------------
__global__ __launch_bounds__(256) void k_onehot_idx(const int* __restrict__ idxarr,
                                                    float* __restrict__ out) {
    const int g = blockIdx.x * 256 + threadIdx.x;      // float4 index
    const int row = g / (NN/4);
    const int j4  = g % (NN/4);
    const int m = idxarr[row];
    float4 o = {0.f, 0.f, 0.f, 0.f};
    if ((m >> 2) == j4) ((float*)&o)[m & 3] = 1.0f;
    ((float4*)out)[g] = o;
}

// ---------------- launcher ----------------
extern "C" void kernel_launch(void* const* d_in, const int* in_sizes, int n_in,
                              void* d_out, int out_size, void* d_ws, size_t ws_size,
                              hipStream_t stream) {
    const float* patches = (const float*)d_in[0];
    const float* task    = (const float*)d_in[1];
    const int*   mask    = (const int*)d_in[2];
    float* out = (float*)d_out;

    // workspace (~28 MB total)
    char* p = (char*)d_ws;
    float* task_n  = (float*)p;  p += (size_t)NB*NT*ND*sizeof(float);    // 6.29 MB
    f16*   t_hi    = (f16*)p;    p += (size_t)NB*NT*ND*sizeof(f16);      // 3.15 MB
    f16*   t_lo    = (f16*)p;    p += (size_t)NB*NT*ND*sizeof(f16);      // 3.15 MB
    float* Rpart   = (float*)p;  p += (size_t)4*NROW*48*sizeof(float);   // 9.44 MB
    float* ssqpart = (float*)p;  p += (size_t)4*NROW*sizeof(float);      // 197 KB
    float* R       = (float*)p;  p += (size_t)NROW*48*sizeof(float);     // 2.36 MB
    float* w       = (float*)p;  p += (size_t)NROW*48*sizeof(float);     // 2.36 MB
    float* pinv    = (float*)p;  p += (size_t)NROW*sizeof(float);        // 49 KB
    float4* part   = (float4*)p; p += (size_t)NROW*16*sizeof(float4);    // 3.15 MB
    int*   idxarr  = (int*)p;    p += (size_t)NROW*sizeof(int);
    int*   flags   = (int*)p;    p += (size_t)NROW*sizeof(int);
    int4*  cand    = (int4*)p;   p += (size_t)NROW*sizeof(int4);

    k_prep_task<<<NB*NT, 256, 0, stream>>>(task, task_n, t_hi, t_lo);
    k_R<<<dim3(NN/64, 4, NB), 256, 0, stream>>>(patches, t_hi, t_lo, Rpart, ssqpart);
    k_combine<<<NROW/256, 256, 0, stream>>>(Rpart, ssqpart, mask, R, w, pinv);
    k_scoreW<<<dim3(NROW/256, 8), 256, 0, stream>>>(w, R, pinv, part);
    k_merge<<<NROW/256, 256, 0, stream>>>(part, idxarr, flags, cand);
    k_rescore<<<NROW, 256, 0, stream>>>(patches, task_n, w, pinv, flags, cand, idxarr);
    k_onehot_idx<<<(NROW*(NN/4))/256, 256, 0, stream>>>(idxarr, out);
}

// Round 7
// 136.060 us; speedup vs baseline: 2.4986x; 1.0652x over previous
//
#include <hip/hip_runtime.h>
#include <math.h>

#define NB 16
#define NN 768
#define NT 48
#define ND 2048
#define NROW (NB*NN)                 // 12288
#define SCALE 0.02209708691207961f   // 1/sqrt(2048)
#define NEGBIG (-3.4028234663852886e38f)
#define TAU 2e-3f
#define KS 512                        // K-slice per ks-block in k_R
#define MSPLIT 16                     // m-chunks in k_scoreW
#define MCH (NN/MSPLIT)               // 48 m per chunk

typedef _Float16 f16;
typedef f16  f16x8 __attribute__((ext_vector_type(8)));
typedef f16  f16x4 __attribute__((ext_vector_type(4)));
typedef float f32x4 __attribute__((ext_vector_type(4)));

__device__ __forceinline__ void stage16(const void* g, void* l) {
    __builtin_amdgcn_global_load_lds(
        (const __attribute__((address_space(1))) unsigned int*)g,
        (__attribute__((address_space(3))) unsigned int*)l, 16, 0, 0);
}

// branchless sorted-desc top-4 insert (value desc, index asc tie-break).
__device__ __forceinline__ void ins4(float v[4], int idx[4], float nv, int ni) {
    const bool b0 = (v[0] > nv) || (v[0] == nv && idx[0] < ni);
    const bool b1 = (v[1] > nv) || (v[1] == nv && idx[1] < ni);
    const bool b2 = (v[2] > nv) || (v[2] == nv && idx[2] < ni);
    const bool b3 = (v[3] > nv) || (v[3] == nv && idx[3] < ni);
    const int pos = (int)b0 + (int)b1 + (int)b2 + (int)b3;
    if (pos <= 3) { if (pos == 3) { v[3] = nv; idx[3] = ni; } else { v[3] = v[2]; idx[3] = idx[2]; } }
    if (pos <= 2) { if (pos == 2) { v[2] = nv; idx[2] = ni; } else { v[2] = v[1]; idx[2] = idx[1]; } }
    if (pos <= 1) { if (pos == 1) { v[1] = nv; idx[1] = ni; } else { v[1] = v[0]; idx[1] = idx[0]; } }
    if (pos == 0) { v[0] = nv; idx[0] = ni; }
}

// ---------------- kernel 1: task rms-norm -> task_n fp32 + t_hi/t_lo f16 ----------------
__global__ __launch_bounds__(256) void k_prep_task(const float* __restrict__ task,
                                                   float* __restrict__ task_n,
                                                   f16* __restrict__ t_hi,
                                                   f16* __restrict__ t_lo) {
    __shared__ float sred[8];
    const int row = blockIdx.x;                 // b*NT + t
    const float4* src = (const float4*)(task + (size_t)row * ND);
    const int tid = threadIdx.x;
    float4 v0 = src[tid];
    float4 v1 = src[tid + 256];
    float s = v0.x*v0.x + v0.y*v0.y + v0.z*v0.z + v0.w*v0.w
            + v1.x*v1.x + v1.y*v1.y + v1.z*v1.z + v1.w*v1.w;
    #pragma unroll
    for (int off = 32; off > 0; off >>= 1) s += __shfl_down(s, off, 64);
    if ((tid & 63) == 0) sred[tid >> 6] = s;
    __syncthreads();
    if (tid == 0)
        sred[4] = 1.0f / sqrtf((sred[0]+sred[1]+sred[2]+sred[3]) * (1.0f/ND) + 1e-6f);
    __syncthreads();
    const float inv = sred[4];
    const size_t o = (size_t)row * ND;
    f16x4 h0, l0, h1, l1;
    float4 n0, n1;
    #pragma unroll
    for (int e = 0; e < 4; e++) {
        float f0 = (&v0.x)[e] * inv, f1 = (&v1.x)[e] * inv;
        (&n0.x)[e] = f0; (&n1.x)[e] = f1;
        f16 a = (f16)f0; h0[e] = a; l0[e] = (f16)(f0 - (float)a);
        f16 c = (f16)f1; h1[e] = c; l1[e] = (f16)(f1 - (float)c);
    }
    *(float4*)&task_n[o + tid*4]          = n0;
    *(float4*)&task_n[o + (tid+256)*4]    = n1;
    *(f16x4*)&t_hi[o + tid*4]             = h0;
    *(f16x4*)&t_lo[o + tid*4]             = l0;
    *(f16x4*)&t_hi[o + (tid+256)*4]       = h1;
    *(f16x4*)&t_lo[o + (tid+256)*4]       = l1;
}

// ---------------- kernel 2: R-partials + sumsq-partials (streams patches ONCE) --------
__global__ __launch_bounds__(256) void k_R(const float* __restrict__ patches,
                                           const f16* __restrict__ t_hi,
                                           const f16* __restrict__ t_lo,
                                           float* __restrict__ Rpart,
                                           float* __restrict__ ssqpart) {
    __shared__ __align__(16) char Ah[64*128], Al[64*128];   // 64 rows x 64 f16
    __shared__ __align__(16) char Bh[48*128], Bl[48*128];   // 48 rows x 64 f16
    const int rt = blockIdx.x, ks = blockIdx.y, b = blockIdx.z;
    const int tid = threadIdx.x, wid = tid >> 6, lane = tid & 63;
    const int q15 = lane & 15, g4 = lane >> 4;
    const int trow = tid >> 2, tq = tid & 3;   // A-load: row 0..63, quad pos
    const int lr = lane >> 3, lgch = (lane & 7) ^ lr;
    const int cxor = q15 & 7;

    const float* gP = patches + ((size_t)(b*NN + rt*64))*ND + ks*KS;
    const f16* gTh = t_hi + (size_t)b*NT*ND + ks*KS;
    const f16* gTl = t_lo + (size_t)b*NT*ND + ks*KS;

    f32x4 acc[3];
    #pragma unroll
    for (int j = 0; j < 3; j++) acc[j] = (f32x4){0.f,0.f,0.f,0.f};
    float ssq = 0.f;

    for (int kk = 0; kk < KS; kk += 64) {
        #pragma unroll
        for (int t2 = 0; t2 < 2; t2++) {
            const int u = wid + 4*t2;
            if (u < 6) {
                stage16(gTh + (size_t)(u*8 + lr)*ND + kk + lgch*8, Bh + u*1024);
                stage16(gTl + (size_t)(u*8 + lr)*ND + kk + lgch*8, Bl + u*1024);
            }
        }
        float4 v[4];
        #pragma unroll
        for (int k = 0; k < 4; k++)
            v[k] = *(const float4*)(gP + (size_t)trow*ND + kk + tq*16 + k*4);
        float lssq = 0.f;
        f16x8 hi8[2], lo8[2];
        #pragma unroll
        for (int k = 0; k < 4; k++)
            #pragma unroll
            for (int e = 0; e < 4; e++) {
                const float f = (&v[k].x)[e];
                lssq += f*f;
                const f16 h = (f16)f;
                hi8[k>>1][(k&1)*4 + e] = h;
                lo8[k>>1][(k&1)*4 + e] = (f16)(f - (float)h);
            }
        lssq += __shfl_xor(lssq, 1, 64);
        lssq += __shfl_xor(lssq, 2, 64);
        if (tq == 0) ssq += lssq;
        const int rb = trow * 128;
        #pragma unroll
        for (int c = 0; c < 2; c++) {
            const int ch = (2*tq + c) ^ (trow & 7);
            *(f16x8*)(Ah + rb + ch*16) = hi8[c];
            *(f16x8*)(Al + rb + ch*16) = lo8[c];
        }
        __syncthreads();
        #pragma unroll
        for (int ksub = 0; ksub < 2; ksub++) {
            const int chb = ((ksub*4 + g4) ^ cxor) << 4;
            const f16x8 a_h = *(const f16x8*)(Ah + (wid*16 + q15)*128 + chb);
            const f16x8 a_l = *(const f16x8*)(Al + (wid*16 + q15)*128 + chb);
            #pragma unroll
            for (int j = 0; j < 3; j++) {
                const f16x8 b_h = *(const f16x8*)(Bh + (j*16 + q15)*128 + chb);
                const f16x8 b_l = *(const f16x8*)(Bl + (j*16 + q15)*128 + chb);
                acc[j] = __builtin_amdgcn_mfma_f32_16x16x32_f16(a_h, b_h, acc[j], 0, 0, 0);
                acc[j] = __builtin_amdgcn_mfma_f32_16x16x32_f16(a_l, b_h, acc[j], 0, 0, 0);
                acc[j] = __builtin_amdgcn_mfma_f32_16x16x32_f16(a_h, b_l, acc[j], 0, 0, 0);
            }
        }
        __syncthreads();
    }
    const int grow = b*NN + rt*64;
    #pragma unroll
    for (int j = 0; j < 3; j++)
        #pragma unroll
        for (int r = 0; r < 4; r++)
            Rpart[((size_t)ks*NROW + grow + wid*16 + g4*4 + r)*48 + j*16 + q15] = acc[j][r];
    if (tq == 0)
        ssqpart[(size_t)ks*NROW + grow + trow] = ssq;
}

// ---------------- kernel 3: combine partials -> pinv, R, w(softmax) ----------------
__global__ __launch_bounds__(256) void k_combine(const float* __restrict__ Rpart,
                                                 const float* __restrict__ ssqpart,
                                                 const int* __restrict__ mask,
                                                 float* __restrict__ R,
                                                 float* __restrict__ w,
                                                 float* __restrict__ pinv) {
    const int r = blockIdx.x * 256 + threadIdx.x;   // 0..12287
    const int b = r / NN;
    float ss = 0.f;
    #pragma unroll
    for (int ks = 0; ks < 4; ks++) ss += ssqpart[(size_t)ks*NROW + r];
    const float pv = 1.0f / sqrtf(ss * (1.0f/ND) + 1e-6f);
    pinv[r] = pv;
    float l[48];
    float mx = -INFINITY;
    #pragma unroll
    for (int t4 = 0; t4 < 12; t4++) {
        float4 a = {0.f,0.f,0.f,0.f};
        #pragma unroll
        for (int ks = 0; ks < 4; ks++) {
            const float4 p = *(const float4*)&Rpart[((size_t)ks*NROW + r)*48 + t4*4];
            a.x += p.x; a.y += p.y; a.z += p.z; a.w += p.w;
        }
        *(float4*)&R[(size_t)r*48 + t4*4] = a;
        #pragma unroll
        for (int e = 0; e < 4; e++) {
            const int t = t4*4 + e;
            const float bias = mask[b*NT + t] ? 0.0f : NEGBIG;
            l[t] = (&a.x)[e] * pv * SCALE + bias;
            mx = fmaxf(mx, l[t]);
        }
    }
    float sum = 0.f;
    #pragma unroll
    for (int t = 0; t < 48; t++) { l[t] = expf(l[t] - mx); sum += l[t]; }
    const float inv = 1.0f / sum;
    #pragma unroll
    for (int t4 = 0; t4 < 12; t4++) {
        float4 o;
        #pragma unroll
        for (int e = 0; e < 4; e++) (&o.x)[e] = l[t4*4 + e] * inv;
        *(float4*)&w[(size_t)r*48 + t4*4] = o;
    }
}

// ---------------- kernel 4: score = pinv[m]*(W.R^T), per-chunk TOP-4, ILP-4 ---------
// block: 256 rows x MCH(=48) m. grid (48 rt, 16 ms) = 768 blocks = 3/CU.
__global__ __launch_bounds__(256) void k_scoreW(const float* __restrict__ w,
                                                const float* __restrict__ R,
                                                const float* __restrict__ pinv,
                                                float4* __restrict__ part) {
    __shared__ float Rl[MCH*48];
    __shared__ float pl[MCH];
    const int rt = blockIdx.x, ms = blockIdx.y;
    const int tid = threadIdx.x;
    const int row = rt*256 + tid;
    const int b = row / NN;                 // constant per block (256 | 768)
    const int m0g = b*NN + ms*MCH;
    for (int u = tid; u < MCH*12; u += 256) {
        const int m = u / 12, t4 = u % 12;
        *(float4*)&Rl[m*48 + t4*4] = *(const float4*)&R[((size_t)(m0g + m))*48 + t4*4];
    }
    if (tid < MCH) pl[tid] = pinv[m0g + tid];
    __syncthreads();
    float4 wr[12];
    #pragma unroll
    for (int t4 = 0; t4 < 12; t4++)
        wr[t4] = *(const float4*)&w[(size_t)row*48 + t4*4];
    float tv[4] = {-INFINITY, -INFINITY, -INFINITY, -INFINITY};
    int   ti[4] = {0x7FFFFFFF, 0x7FFFFFFF, 0x7FFFFFFF, 0x7FFFFFFF};
    #pragma unroll 2
    for (int m = 0; m < MCH; m += 4) {
        // 4 independent FMA chains (ILP-4 kills the dep-latency stall)
        float s0 = 0.f, s1 = 0.f, s2 = 0.f, s3 = 0.f;
        #pragma unroll
        for (int t4 = 0; t4 < 12; t4++) {
            const float4 r0 = *(const float4*)&Rl[(m+0)*48 + t4*4];
            const float4 r1 = *(const float4*)&Rl[(m+1)*48 + t4*4];
            const float4 r2 = *(const float4*)&Rl[(m+2)*48 + t4*4];
            const float4 r3 = *(const float4*)&Rl[(m+3)*48 + t4*4];
            const float4 wv = wr[t4];
            s0 = fmaf(wv.x, r0.x, s0); s1 = fmaf(wv.x, r1.x, s1);
            s2 = fmaf(wv.x, r2.x, s2); s3 = fmaf(wv.x, r3.x, s3);
            s0 = fmaf(wv.y, r0.y, s0); s1 = fmaf(wv.y, r1.y, s1);
            s2 = fmaf(wv.y, r2.y, s2); s3 = fmaf(wv.y, r3.y, s3);
            s0 = fmaf(wv.z, r0.z, s0); s1 = fmaf(wv.z, r1.z, s1);
            s2 = fmaf(wv.z, r2.z, s2); s3 = fmaf(wv.z, r3.z, s3);
            s0 = fmaf(wv.w, r0.w, s0); s1 = fmaf(wv.w, r1.w, s1);
            s2 = fmaf(wv.w, r2.w, s2); s3 = fmaf(wv.w, r3.w, s3);
        }
        s0 *= pl[m+0]; s1 *= pl[m+1]; s2 *= pl[m+2]; s3 *= pl[m+3];
        const int mg = m0g - b*NN + m;      // ms*MCH + m
        ins4(tv, ti, s0, mg+0);
        ins4(tv, ti, s1, mg+1);
        ins4(tv, ti, s2, mg+2);
        ins4(tv, ti, s3, mg+3);
    }
    part[((size_t)row*MSPLIT + ms)*2]     = make_float4(tv[0], __int_as_float(ti[0]), tv[1], __int_as_float(ti[1]));
    part[((size_t)row*MSPLIT + ms)*2 + 1] = make_float4(tv[2], __int_as_float(ti[2]), tv[3], __int_as_float(ti[3]));
}

// ---------------- kernel 5: merge chunks' top-4 -> global top-4, flags, cand ------
__global__ __launch_bounds__(256) void k_merge(const float4* __restrict__ part,
                                               int* __restrict__ idxarr,
                                               int* __restrict__ flags,
                                               int4* __restrict__ cand) {
    const int r = blockIdx.x * 256 + threadIdx.x;
    float tv[4] = {-INFINITY, -INFINITY, -INFINITY, -INFINITY};
    int   ti[4] = {0x7FFFFFFF, 0x7FFFFFFF, 0x7FFFFFFF, 0x7FFFFFFF};
    #pragma unroll
    for (int t = 0; t < MSPLIT; t++) {
        const float4 e0 = part[((size_t)r*MSPLIT + t)*2];
        const float4 e1 = part[((size_t)r*MSPLIT + t)*2 + 1];
        ins4(tv, ti, e0.x, __float_as_int(e0.y));
        ins4(tv, ti, e0.z, __float_as_int(e0.w));
        ins4(tv, ti, e1.x, __float_as_int(e1.y));
        ins4(tv, ti, e1.z, __float_as_int(e1.w));
    }
    idxarr[r] = ti[0];
    int fl = 0;
    if (tv[0] - tv[1] < TAU) fl = 1;
    if (tv[0] - tv[3] < TAU) fl = 2;       // pathological: need full scan
    flags[r] = fl;
    if (fl) cand[r] = make_int4(ti[0], ti[1], ti[2], ti[3]);
}

// ---------------- kernel 6: exact fp32 rescore (wave-parallel, candidates only) -----
__global__ __launch_bounds__(256) void k_rescore(const float* __restrict__ patches,
                                                 const float* __restrict__ task_n,
                                                 const float* __restrict__ w,
                                                 const float* __restrict__ pinv,
                                                 const int* __restrict__ flags,
                                                 const int4* __restrict__ cand,
                                                 int* __restrict__ idxarr) {
    const int row = blockIdx.x;
    const int fl = flags[row];
    if (!fl) return;
    __shared__ float wl[48];
    __shared__ float qrow[ND];
    __shared__ float sv[4];
    __shared__ int   si[4];
    __shared__ int   sc[4];
    const int b = row / NN;
    const int tid = threadIdx.x, wid = tid >> 6, lane = tid & 63;
    if (tid < 12) *(float4*)&wl[tid*4] = *(const float4*)&w[(size_t)row*48 + tid*4];
    if (tid < 4) {
        const int4 c4 = cand[row];
        sc[tid] = (tid == 0) ? c4.x : (tid == 1) ? c4.y : (tid == 2) ? c4.z : c4.w;
    }
    __syncthreads();
    {
        float q[8] = {0.f,0.f,0.f,0.f,0.f,0.f,0.f,0.f};
        for (int t = 0; t < NT; t++) {
            const float wt = wl[t];
            const float* Tn = task_n + ((size_t)(b*NT + t))*ND + tid*8;
            const float4 u0 = *(const float4*)Tn;
            const float4 u1 = *(const float4*)(Tn + 4);
            q[0] = fmaf(wt, u0.x, q[0]); q[1] = fmaf(wt, u0.y, q[1]);
            q[2] = fmaf(wt, u0.z, q[2]); q[3] = fmaf(wt, u0.w, q[3]);
            q[4] = fmaf(wt, u1.x, q[4]); q[5] = fmaf(wt, u1.y, q[5]);
            q[6] = fmaf(wt, u1.z, q[6]); q[7] = fmaf(wt, u1.w, q[7]);
        }
        #pragma unroll
        for (int e = 0; e < 8; e++) qrow[tid*8 + e] = q[e];
    }
    __syncthreads();

    if (fl == 1) {
        const int c = sc[wid];
        const float* prow = patches + ((size_t)b*NN + c)*ND + lane*32;
        const float* qp = qrow + lane*32;
        float s = 0.f;
        #pragma unroll
        for (int k = 0; k < 8; k++) {
            const float4 p = *(const float4*)(prow + k*4);
            const float4 qv = *(const float4*)(qp + k*4);
            s = fmaf(p.x, qv.x, s); s = fmaf(p.y, qv.y, s);
            s = fmaf(p.z, qv.z, s); s = fmaf(p.w, qv.w, s);
        }
        #pragma unroll
        for (int off = 32; off > 0; off >>= 1) s += __shfl_down(s, off, 64);
        if (lane == 0) { sv[wid] = s * pinv[b*NN + c]; si[wid] = c; }
        __syncthreads();
        if (tid == 0) {
            float bv = sv[0]; int bm = si[0];
            #pragma unroll
            for (int k = 1; k < 4; k++) {
                if (sv[k] > bv || (sv[k] == bv && si[k] < bm)) { bv = sv[k]; bm = si[k]; }
            }
            idxarr[row] = bm;
        }
    } else {
        float bv = -INFINITY; int bm = 0;
        for (int m = wid; m < NN; m += 4) {
            const float* prow = patches + ((size_t)b*NN + m)*ND + lane*32;
            const float* qp = qrow + lane*32;
            float s = 0.f;
            #pragma unroll
            for (int k = 0; k < 8; k++) {
                const float4 p = *(const float4*)(prow + k*4);
                const float4 qv = *(const float4*)(qp + k*4);
                s = fmaf(p.x, qv.x, s); s = fmaf(p.y, qv.y, s);
                s = fmaf(p.z, qv.z, s); s = fmaf(p.w, qv.w, s);
            }
            #pragma unroll
            for (int off = 32; off > 0; off >>= 1) s += __shfl_down(s, off, 64);
            if (lane == 0) {
                s *= pinv[b*NN + m];
                if (s > bv) { bv = s; bm = m; }
            }
        }
        if (lane == 0) { sv[wid] = bv; si[wid] = bm; }
        __syncthreads();
        if (tid == 0) {
            float v = sv[0]; int bi = si[0];
            #pragma unroll
            for (int k = 1; k < 4; k++) {
                if (sv[k] > v || (sv[k] == v && si[k] < bi)) { v = sv[k]; bi = si[k]; }
            }
            idxarr[row] = bi;
        }
    }
}

// ---------------- kernel 7: one-hot from idx ----------------
__global__ __launch_bounds__(256) void k_onehot_idx(const int* __restrict__ idxarr,
                                                    float* __restrict__ out) {
    const int g = blockIdx.x * 256 + threadIdx.x;      // float4 index
    const int row = g / (NN/4);
    const int j4  = g % (NN/4);
    const int m = idxarr[row];
    float4 o = {0.f, 0.f, 0.f, 0.f};
    if ((m >> 2) == j4) ((float*)&o)[m & 3] = 1.0f;
    ((float4*)out)[g] = o;
}

// ---------------- launcher ----------------
extern "C" void kernel_launch(void* const* d_in, const int* in_sizes, int n_in,
                              void* d_out, int out_size, void* d_ws, size_t ws_size,
                              hipStream_t stream) {
    const float* patches = (const float*)d_in[0];
    const float* task    = (const float*)d_in[1];
    const int*   mask    = (const int*)d_in[2];
    float* out = (float*)d_out;

    char* p = (char*)d_ws;
    float* task_n  = (float*)p;  p += (size_t)NB*NT*ND*sizeof(float);    // 6.29 MB
    f16*   t_hi    = (f16*)p;    p += (size_t)NB*NT*ND*sizeof(f16);      // 3.15 MB
    f16*   t_lo    = (f16*)p;    p += (size_t)NB*NT*ND*sizeof(f16);      // 3.15 MB
    float* Rpart   = (float*)p;  p += (size_t)4*NROW*48*sizeof(float);   // 9.44 MB
    float* ssqpart = (float*)p;  p += (size_t)4*NROW*sizeof(float);      // 197 KB
    float* R       = (float*)p;  p += (size_t)NROW*48*sizeof(float);     // 2.36 MB
    float* w       = (float*)p;  p += (size_t)NROW*48*sizeof(float);     // 2.36 MB
    float* pinv    = (float*)p;  p += (size_t)NROW*sizeof(float);        // 49 KB
    float4* part   = (float4*)p; p += (size_t)NROW*MSPLIT*2*sizeof(float4); // 6.3 MB
    int*   idxarr  = (int*)p;    p += (size_t)NROW*sizeof(int);
    int*   flags   = (int*)p;    p += (size_t)NROW*sizeof(int);
    int4*  cand    = (int4*)p;   p += (size_t)NROW*sizeof(int4);

    k_prep_task<<<NB*NT, 256, 0, stream>>>(task, task_n, t_hi, t_lo);
    k_R<<<dim3(NN/64, 4, NB), 256, 0, stream>>>(patches, t_hi, t_lo, Rpart, ssqpart);
    k_combine<<<NROW/256, 256, 0, stream>>>(Rpart, ssqpart, mask, R, w, pinv);
    k_scoreW<<<dim3(NROW/256, MSPLIT), 256, 0, stream>>>(w, R, pinv, part);
    k_merge<<<NROW/256, 256, 0, stream>>>(part, idxarr, flags, cand);
    k_rescore<<<NROW, 256, 0, stream>>>(patches, task_n, w, pinv, flags, cand, idxarr);
    k_onehot_idx<<<(NROW*(NN/4))/256, 256, 0, stream>>>(idxarr, out);
}

// Round 8
// 116.939 us; speedup vs baseline: 2.9071x; 1.1635x over previous
//
#include <hip/hip_runtime.h>
#include <math.h>

#define NB 16
#define NN 768
#define NT 48
#define ND 2048
#define NROW (NB*NN)                 // 12288
#define SCALE 0.02209708691207961f   // 1/sqrt(2048)
#define NEGBIG (-3.4028234663852886e38f)
#define TAU 2e-3f
#define KS 512                        // K-slice per ks-block in k_R
#define MSPLIT 16                     // m-chunks in k_scoreW
#define MCH (NN/MSPLIT)               // 48 m per chunk

typedef _Float16 f16;
typedef f16  f16x8 __attribute__((ext_vector_type(8)));
typedef f16  f16x4 __attribute__((ext_vector_type(4)));
typedef float f32x4 __attribute__((ext_vector_type(4)));

__device__ __forceinline__ void stage16(const void* g, void* l) {
    __builtin_amdgcn_global_load_lds(
        (const __attribute__((address_space(1))) unsigned int*)g,
        (__attribute__((address_space(3))) unsigned int*)l, 16, 0, 0);
}

// branchless sorted-desc top-4 insert (value desc, index asc tie-break).
__device__ __forceinline__ void ins4(float v[4], int idx[4], float nv, int ni) {
    const bool b0 = (v[0] > nv) || (v[0] == nv && idx[0] < ni);
    const bool b1 = (v[1] > nv) || (v[1] == nv && idx[1] < ni);
    const bool b2 = (v[2] > nv) || (v[2] == nv && idx[2] < ni);
    const bool b3 = (v[3] > nv) || (v[3] == nv && idx[3] < ni);
    const int pos = (int)b0 + (int)b1 + (int)b2 + (int)b3;
    if (pos <= 3) { if (pos == 3) { v[3] = nv; idx[3] = ni; } else { v[3] = v[2]; idx[3] = idx[2]; } }
    if (pos <= 2) { if (pos == 2) { v[2] = nv; idx[2] = ni; } else { v[2] = v[1]; idx[2] = idx[1]; } }
    if (pos <= 1) { if (pos == 1) { v[1] = nv; idx[1] = ni; } else { v[1] = v[0]; idx[1] = idx[0]; } }
    if (pos == 0) { v[0] = nv; idx[0] = ni; }
}

// ---------------- kernel 1: task rms-norm -> task_n fp32 + t_hi/t_lo f16 ----------------
__global__ __launch_bounds__(256) void k_prep_task(const float* __restrict__ task,
                                                   float* __restrict__ task_n,
                                                   f16* __restrict__ t_hi,
                                                   f16* __restrict__ t_lo) {
    __shared__ float sred[8];
    const int row = blockIdx.x;                 // b*NT + t
    const float4* src = (const float4*)(task + (size_t)row * ND);
    const int tid = threadIdx.x;
    float4 v0 = src[tid];
    float4 v1 = src[tid + 256];
    float s = v0.x*v0.x + v0.y*v0.y + v0.z*v0.z + v0.w*v0.w
            + v1.x*v1.x + v1.y*v1.y + v1.z*v1.z + v1.w*v1.w;
    #pragma unroll
    for (int off = 32; off > 0; off >>= 1) s += __shfl_down(s, off, 64);
    if ((tid & 63) == 0) sred[tid >> 6] = s;
    __syncthreads();
    if (tid == 0)
        sred[4] = 1.0f / sqrtf((sred[0]+sred[1]+sred[2]+sred[3]) * (1.0f/ND) + 1e-6f);
    __syncthreads();
    const float inv = sred[4];
    const size_t o = (size_t)row * ND;
    f16x4 h0, l0, h1, l1;
    float4 n0, n1;
    #pragma unroll
    for (int e = 0; e < 4; e++) {
        float f0 = (&v0.x)[e] * inv, f1 = (&v1.x)[e] * inv;
        (&n0.x)[e] = f0; (&n1.x)[e] = f1;
        f16 a = (f16)f0; h0[e] = a; l0[e] = (f16)(f0 - (float)a);
        f16 c = (f16)f1; h1[e] = c; l1[e] = (f16)(f1 - (float)c);
    }
    *(float4*)&task_n[o + tid*4]          = n0;
    *(float4*)&task_n[o + (tid+256)*4]    = n1;
    *(f16x4*)&t_hi[o + tid*4]             = h0;
    *(f16x4*)&t_lo[o + tid*4]             = l0;
    *(f16x4*)&t_hi[o + (tid+256)*4]       = h1;
    *(f16x4*)&t_lo[o + (tid+256)*4]       = l1;
}

// ---------------- kernel 2: R-partials + sumsq-partials (streams patches ONCE) --------
// software-pipelined: A-prefetch in regs across a raw s_barrier (no vmcnt drain).
__global__ __launch_bounds__(256) void k_R(const float* __restrict__ patches,
                                           const f16* __restrict__ t_hi,
                                           const f16* __restrict__ t_lo,
                                           float* __restrict__ Rpart,
                                           float* __restrict__ ssqpart) {
    __shared__ __align__(16) char Ah[64*128], Al[64*128];   // 8 KB each
    __shared__ __align__(16) char Bh[48*128], Bl[48*128];   // 6 KB each (28 KB total)
    const int rt = blockIdx.x, ks = blockIdx.y, b = blockIdx.z;
    const int tid = threadIdx.x, wid = tid >> 6, lane = tid & 63;
    const int q15 = lane & 15, g4 = lane >> 4;
    const int trow = tid >> 2, tq = tid & 3;   // A-load: row 0..63, quad pos
    const int lr = lane >> 3, lgch = (lane & 7) ^ lr;
    const int cxor = q15 & 7;

    const float* gP = patches + ((size_t)(b*NN + rt*64))*ND + ks*KS;
    const f16* gTh = t_hi + (size_t)b*NT*ND + ks*KS;
    const f16* gTl = t_lo + (size_t)b*NT*ND + ks*KS;

    f32x4 acc[3];
    #pragma unroll
    for (int j = 0; j < 3; j++) acc[j] = (f32x4){0.f,0.f,0.f,0.f};
    float ssq = 0.f;

    const float* aptr = gP + (size_t)trow*ND + tq*16;
    float4 v[4], vn[4];
    #pragma unroll
    for (int k = 0; k < 4; k++) v[k] = *(const float4*)(aptr + k*4);

    for (int kk = 0; kk < KS; kk += 64) {
        // stage B (tiny, L2-hot)
        #pragma unroll
        for (int t2 = 0; t2 < 2; t2++) {
            const int u = wid + 4*t2;
            if (u < 6) {
                stage16(gTh + (size_t)(u*8 + lr)*ND + kk + lgch*8, Bh + u*1024);
                stage16(gTl + (size_t)(u*8 + lr)*ND + kk + lgch*8, Bl + u*1024);
            }
        }
        // split current A regs -> sumsq + f16 hi/lo -> swizzled LDS
        float lssq = 0.f;
        f16x8 hi8[2], lo8[2];
        #pragma unroll
        for (int k = 0; k < 4; k++)
            #pragma unroll
            for (int e = 0; e < 4; e++) {
                const float f = (&v[k].x)[e];
                lssq += f*f;
                const f16 h = (f16)f;
                hi8[k>>1][(k&1)*4 + e] = h;
                lo8[k>>1][(k&1)*4 + e] = (f16)(f - (float)h);
            }
        lssq += __shfl_xor(lssq, 1, 64);
        lssq += __shfl_xor(lssq, 2, 64);
        if (tq == 0) ssq += lssq;
        const int rb = trow * 128;
        #pragma unroll
        for (int c = 0; c < 2; c++) {
            const int ch = (2*tq + c) ^ (trow & 7);
            *(f16x8*)(Ah + rb + ch*16) = hi8[c];
            *(f16x8*)(Al + rb + ch*16) = lo8[c];
        }
        __syncthreads();   // full drain: B stage16 + A ds_writes visible
        // prefetch next A tile (in flight across MFMA + raw barrier)
        if (kk + 64 < KS) {
            #pragma unroll
            for (int k = 0; k < 4; k++)
                vn[k] = *(const float4*)(aptr + kk + 64 + k*4);
        }
        #pragma unroll
        for (int ksub = 0; ksub < 2; ksub++) {
            const int chb = ((ksub*4 + g4) ^ cxor) << 4;
            const f16x8 a_h = *(const f16x8*)(Ah + (wid*16 + q15)*128 + chb);
            const f16x8 a_l = *(const f16x8*)(Al + (wid*16 + q15)*128 + chb);
            #pragma unroll
            for (int j = 0; j < 3; j++) {
                const f16x8 b_h = *(const f16x8*)(Bh + (j*16 + q15)*128 + chb);
                const f16x8 b_l = *(const f16x8*)(Bl + (j*16 + q15)*128 + chb);
                acc[j] = __builtin_amdgcn_mfma_f32_16x16x32_f16(a_h, b_h, acc[j], 0, 0, 0);
                acc[j] = __builtin_amdgcn_mfma_f32_16x16x32_f16(a_l, b_h, acc[j], 0, 0, 0);
                acc[j] = __builtin_amdgcn_mfma_f32_16x16x32_f16(a_h, b_l, acc[j], 0, 0, 0);
            }
        }
        // raw barrier: LDS reads are already consumed into regs (lgkm-forced
        // before MFMA), so no vmcnt(0) drain needed -> prefetch stays in flight
        __builtin_amdgcn_s_barrier();
        __builtin_amdgcn_sched_barrier(0);
        #pragma unroll
        for (int k = 0; k < 4; k++) v[k] = vn[k];
    }
    const int grow = b*NN + rt*64;
    #pragma unroll
    for (int j = 0; j < 3; j++)
        #pragma unroll
        for (int r = 0; r < 4; r++)
            Rpart[((size_t)ks*NROW + grow + wid*16 + g4*4 + r)*48 + j*16 + q15] = acc[j][r];
    if (tq == 0)
        ssqpart[(size_t)ks*NROW + grow + trow] = ssq;
}

// ---------------- kernel 3: combine partials -> pinv, R, w(softmax) ----------------
__global__ __launch_bounds__(256) void k_combine(const float* __restrict__ Rpart,
                                                 const float* __restrict__ ssqpart,
                                                 const int* __restrict__ mask,
                                                 float* __restrict__ R,
                                                 float* __restrict__ w,
                                                 float* __restrict__ pinv) {
    const int r = blockIdx.x * 256 + threadIdx.x;   // 0..12287
    const int b = r / NN;
    float ss = 0.f;
    #pragma unroll
    for (int ks = 0; ks < 4; ks++) ss += ssqpart[(size_t)ks*NROW + r];
    const float pv = 1.0f / sqrtf(ss * (1.0f/ND) + 1e-6f);
    pinv[r] = pv;
    float l[48];
    float mx = -INFINITY;
    #pragma unroll
    for (int t4 = 0; t4 < 12; t4++) {
        float4 a = {0.f,0.f,0.f,0.f};
        #pragma unroll
        for (int ks = 0; ks < 4; ks++) {
            const float4 p = *(const float4*)&Rpart[((size_t)ks*NROW + r)*48 + t4*4];
            a.x += p.x; a.y += p.y; a.z += p.z; a.w += p.w;
        }
        *(float4*)&R[(size_t)r*48 + t4*4] = a;
        #pragma unroll
        for (int e = 0; e < 4; e++) {
            const int t = t4*4 + e;
            const float bias = mask[b*NT + t] ? 0.0f : NEGBIG;
            l[t] = (&a.x)[e] * pv * SCALE + bias;
            mx = fmaxf(mx, l[t]);
        }
    }
    float sum = 0.f;
    #pragma unroll
    for (int t = 0; t < 48; t++) { l[t] = expf(l[t] - mx); sum += l[t]; }
    const float inv = 1.0f / sum;
    #pragma unroll
    for (int t4 = 0; t4 < 12; t4++) {
        float4 o;
        #pragma unroll
        for (int e = 0; e < 4; e++) (&o.x)[e] = l[t4*4 + e] * inv;
        *(float4*)&w[(size_t)r*48 + t4*4] = o;
    }
}

// ---------------- kernel 4: score = pinv[m]*(W.R^T), per-chunk TOP-4, ILP-4 ---------
__global__ __launch_bounds__(256) void k_scoreW(const float* __restrict__ w,
                                                const float* __restrict__ R,
                                                const float* __restrict__ pinv,
                                                float4* __restrict__ part) {
    __shared__ float Rl[MCH*48];
    __shared__ float pl[MCH];
    const int rt = blockIdx.x, ms = blockIdx.y;
    const int tid = threadIdx.x;
    const int row = rt*256 + tid;
    const int b = row / NN;                 // constant per block (256 | 768)
    const int m0g = b*NN + ms*MCH;
    for (int u = tid; u < MCH*12; u += 256) {
        const int m = u / 12, t4 = u % 12;
        *(float4*)&Rl[m*48 + t4*4] = *(const float4*)&R[((size_t)(m0g + m))*48 + t4*4];
    }
    if (tid < MCH) pl[tid] = pinv[m0g + tid];
    __syncthreads();
    float4 wr[12];
    #pragma unroll
    for (int t4 = 0; t4 < 12; t4++)
        wr[t4] = *(const float4*)&w[(size_t)row*48 + t4*4];
    float tv[4] = {-INFINITY, -INFINITY, -INFINITY, -INFINITY};
    int   ti[4] = {0x7FFFFFFF, 0x7FFFFFFF, 0x7FFFFFFF, 0x7FFFFFFF};
    #pragma unroll 2
    for (int m = 0; m < MCH; m += 4) {
        float s0 = 0.f, s1 = 0.f, s2 = 0.f, s3 = 0.f;
        #pragma unroll
        for (int t4 = 0; t4 < 12; t4++) {
            const float4 r0 = *(const float4*)&Rl[(m+0)*48 + t4*4];
            const float4 r1 = *(const float4*)&Rl[(m+1)*48 + t4*4];
            const float4 r2 = *(const float4*)&Rl[(m+2)*48 + t4*4];
            const float4 r3 = *(const float4*)&Rl[(m+3)*48 + t4*4];
            const float4 wv = wr[t4];
            s0 = fmaf(wv.x, r0.x, s0); s1 = fmaf(wv.x, r1.x, s1);
            s2 = fmaf(wv.x, r2.x, s2); s3 = fmaf(wv.x, r3.x, s3);
            s0 = fmaf(wv.y, r0.y, s0); s1 = fmaf(wv.y, r1.y, s1);
            s2 = fmaf(wv.y, r2.y, s2); s3 = fmaf(wv.y, r3.y, s3);
            s0 = fmaf(wv.z, r0.z, s0); s1 = fmaf(wv.z, r1.z, s1);
            s2 = fmaf(wv.z, r2.z, s2); s3 = fmaf(wv.z, r3.z, s3);
            s0 = fmaf(wv.w, r0.w, s0); s1 = fmaf(wv.w, r1.w, s1);
            s2 = fmaf(wv.w, r2.w, s2); s3 = fmaf(wv.w, r3.w, s3);
        }
        s0 *= pl[m+0]; s1 *= pl[m+1]; s2 *= pl[m+2]; s3 *= pl[m+3];
        const int mg = ms*MCH + m;
        ins4(tv, ti, s0, mg+0);
        ins4(tv, ti, s1, mg+1);
        ins4(tv, ti, s2, mg+2);
        ins4(tv, ti, s3, mg+3);
    }
    part[((size_t)row*MSPLIT + ms)*2]     = make_float4(tv[0], __int_as_float(ti[0]), tv[1], __int_as_float(ti[1]));
    part[((size_t)row*MSPLIT + ms)*2 + 1] = make_float4(tv[2], __int_as_float(ti[2]), tv[3], __int_as_float(ti[3]));
}

// ---------------- kernel 5: fused merge + exact rescore + one-hot write ----------
// one block per row. 64-lane ballot merge of 64 chunk-candidates.
__global__ __launch_bounds__(256) void k_final(const float* __restrict__ patches,
                                               const float* __restrict__ task_n,
                                               const float* __restrict__ w,
                                               const float* __restrict__ pinv,
                                               const float4* __restrict__ part,
                                               float* __restrict__ out) {
    __shared__ float qrow[ND];
    __shared__ float wl[48];
    __shared__ int   scand[64];
    __shared__ float swv[4];
    __shared__ int   swi[4];
    __shared__ int   s_idx, s_cnt;
    const int row = blockIdx.x;
    const int b = row / NN;
    const int tid = threadIdx.x, wid = tid >> 6, lane = tid & 63;

    if (wid == 0) {
        // lane l holds candidate l: chunk l>>2, rank l&3
        const float2 e = ((const float2*)part)[(size_t)row*64 + lane];
        const float myv = e.x;
        const int   myi = __float_as_int(e.y);
        float v = myv; int i = myi;
        #pragma unroll
        for (int off = 1; off <= 32; off <<= 1) {
            const float ov = __shfl_xor(v, off, 64);
            const int   oi = __shfl_xor(i, off, 64);
            if (ov > v || (ov == v && oi < i)) { v = ov; i = oi; }
        }
        // v,i = global approx top-1 (all lanes agree)
        const bool in_tau = (myv >= v - TAU);
        const unsigned long long mb  = __ballot(in_tau);
        const unsigned long long mb4 = __ballot(in_tau && ((lane & 3) == 3));
        if (lane == 0) {
            s_idx = i;
            s_cnt = mb4 ? 999 : __popcll(mb);   // 999 => chunk 4th within TAU => full scan
        }
        if (in_tau) {
            const unsigned long long below = mb & ((lane == 0) ? 0ull : (~0ull >> (64 - lane)));
            scand[__popcll(below)] = myi;
        }
    }
    __syncthreads();
    const int cnt = s_cnt;
    if (cnt > 1) {
        if (tid < 12) *(float4*)&wl[tid*4] = *(const float4*)&w[(size_t)row*48 + tid*4];
        __syncthreads();
        {   // q = w . task_n (exact fp32), cooperative: thread owns 8 floats
            float q[8] = {0.f,0.f,0.f,0.f,0.f,0.f,0.f,0.f};
            for (int t = 0; t < NT; t++) {
                const float wt = wl[t];
                const float* Tn = task_n + ((size_t)(b*NT + t))*ND + tid*8;
                const float4 u0 = *(const float4*)Tn;
                const float4 u1 = *(const float4*)(Tn + 4);
                q[0] = fmaf(wt, u0.x, q[0]); q[1] = fmaf(wt, u0.y, q[1]);
                q[2] = fmaf(wt, u0.z, q[2]); q[3] = fmaf(wt, u0.w, q[3]);
                q[4] = fmaf(wt, u1.x, q[4]); q[5] = fmaf(wt, u1.y, q[5]);
                q[6] = fmaf(wt, u1.z, q[6]); q[7] = fmaf(wt, u1.w, q[7]);
            }
            #pragma unroll
            for (int e2 = 0; e2 < 8; e2++) qrow[tid*8 + e2] = q[e2];
        }
        __syncthreads();
        float bw = -INFINITY; int bi = 0x7FFFFFFF;
        if (cnt != 999) {
            // exact rescore of the <=64 candidates; wave wid takes c = wid, wid+4, ...
            for (int c = wid; c < cnt; c += 4) {
                const int m = scand[c];
                const float* prow = patches + ((size_t)b*NN + m)*ND + lane*32;
                const float* qp = qrow + lane*32;
                float s = 0.f;
                #pragma unroll
                for (int k = 0; k < 8; k++) {
                    const float4 p = *(const float4*)(prow + k*4);
                    const float4 qv = *(const float4*)(qp + k*4);
                    s = fmaf(p.x, qv.x, s); s = fmaf(p.y, qv.y, s);
                    s = fmaf(p.z, qv.z, s); s = fmaf(p.w, qv.w, s);
                }
                #pragma unroll
                for (int off = 32; off > 0; off >>= 1) s += __shfl_down(s, off, 64);
                if (lane == 0) {
                    s *= pinv[b*NN + m];
                    if (s > bw || (s == bw && m < bi)) { bw = s; bi = m; }
                }
            }
        } else {
            // pathological: full exact scan
            for (int m = wid; m < NN; m += 4) {
                const float* prow = patches + ((size_t)b*NN + m)*ND + lane*32;
                const float* qp = qrow + lane*32;
                float s = 0.f;
                #pragma unroll
                for (int k = 0; k < 8; k++) {
                    const float4 p = *(const float4*)(prow + k*4);
                    const float4 qv = *(const float4*)(qp + k*4);
                    s = fmaf(p.x, qv.x, s); s = fmaf(p.y, qv.y, s);
                    s = fmaf(p.z, qv.z, s); s = fmaf(p.w, qv.w, s);
                }
                #pragma unroll
                for (int off = 32; off > 0; off >>= 1) s += __shfl_down(s, off, 64);
                if (lane == 0) {
                    s *= pinv[b*NN + m];
                    if (s > bw || (s == bw && m < bi)) { bw = s; bi = m; }
                }
            }
        }
        if (lane == 0) { swv[wid] = bw; swi[wid] = bi; }
        __syncthreads();
        if (tid == 0) {
            float v = swv[0]; int i = swi[0];
            #pragma unroll
            for (int k = 1; k < 4; k++) {
                if (swv[k] > v || (swv[k] == v && swi[k] < i)) { v = swv[k]; i = swi[k]; }
            }
            s_idx = i;
        }
        __syncthreads();
    }
    // one-hot write: 192 float4 per row
    const int m = s_idx;
    if (tid < 192) {
        float4 o = {0.f, 0.f, 0.f, 0.f};
        if ((m >> 2) == tid) ((float*)&o)[m & 3] = 1.0f;
        ((float4*)(out + (size_t)row*NN))[tid] = o;
    }
}

// ---------------- launcher ----------------
extern "C" void kernel_launch(void* const* d_in, const int* in_sizes, int n_in,
                              void* d_out, int out_size, void* d_ws, size_t ws_size,
                              hipStream_t stream) {
    const float* patches = (const float*)d_in[0];
    const float* task    = (const float*)d_in[1];
    const int*   mask    = (const int*)d_in[2];
    float* out = (float*)d_out;

    char* p = (char*)d_ws;
    float* task_n  = (float*)p;  p += (size_t)NB*NT*ND*sizeof(float);    // 6.29 MB
    f16*   t_hi    = (f16*)p;    p += (size_t)NB*NT*ND*sizeof(f16);      // 3.15 MB
    f16*   t_lo    = (f16*)p;    p += (size_t)NB*NT*ND*sizeof(f16);      // 3.15 MB
    float* Rpart   = (float*)p;  p += (size_t)4*NROW*48*sizeof(float);   // 9.44 MB
    float* ssqpart = (float*)p;  p += (size_t)4*NROW*sizeof(float);      // 197 KB
    float* R       = (float*)p;  p += (size_t)NROW*48*sizeof(float);     // 2.36 MB
    float* w       = (float*)p;  p += (size_t)NROW*48*sizeof(float);     // 2.36 MB
    float* pinv    = (float*)p;  p += (size_t)NROW*sizeof(float);        // 49 KB
    float4* part   = (float4*)p; p += (size_t)NROW*MSPLIT*2*sizeof(float4); // 6.3 MB

    k_prep_task<<<NB*NT, 256, 0, stream>>>(task, task_n, t_hi, t_lo);
    k_R<<<dim3(NN/64, 4, NB), 256, 0, stream>>>(patches, t_hi, t_lo, Rpart, ssqpart);
    k_combine<<<NROW/256, 256, 0, stream>>>(Rpart, ssqpart, mask, R, w, pinv);
    k_scoreW<<<dim3(NROW/256, MSPLIT), 256, 0, stream>>>(w, R, pinv, part);
    k_final<<<NROW, 256, 0, stream>>>(patches, task_n, w, pinv, part, out);
}

// Round 9
// 98.685 us; speedup vs baseline: 3.4448x; 1.1850x over previous
//
#include <hip/hip_runtime.h>
#include <math.h>

#define NB 16
#define NN 768
#define NT 48
#define ND 2048
#define NROW (NB*NN)                 // 12288
#define SCALE 0.02209708691207961f   // 1/sqrt(2048)
#define NEGBIG (-3.4028234663852886e38f)
#define TAU 2e-3f
#define KS 512                        // K-slice per ks-block in k_R
#define MSPLIT 16                     // m-chunks in k_scoreW
#define MCH (NN/MSPLIT)               // 48 m per chunk

typedef _Float16 f16;
typedef f16  f16x8 __attribute__((ext_vector_type(8)));
typedef f16  f16x4 __attribute__((ext_vector_type(4)));
typedef float f32x4 __attribute__((ext_vector_type(4)));

__device__ __forceinline__ void stage16(const void* g, void* l) {
    __builtin_amdgcn_global_load_lds(
        (const __attribute__((address_space(1))) unsigned int*)g,
        (__attribute__((address_space(3))) unsigned int*)l, 16, 0, 0);
}

// monotone top-4 insert: valid when calls use ascending index ni within a scan
// (tie => keep existing smaller index). value-only compares.
__device__ __forceinline__ void ins4m(float v[4], int idx[4], float nv, int ni) {
    const bool b0 = (v[0] >= nv);
    const bool b1 = (v[1] >= nv);
    const bool b2 = (v[2] >= nv);
    const bool b3 = (v[3] >= nv);
    const int pos = (int)b0 + (int)b1 + (int)b2 + (int)b3;
    if (pos <= 3) { if (pos == 3) { v[3] = nv; idx[3] = ni; } else { v[3] = v[2]; idx[3] = idx[2]; } }
    if (pos <= 2) { if (pos == 2) { v[2] = nv; idx[2] = ni; } else { v[2] = v[1]; idx[2] = idx[1]; } }
    if (pos <= 1) { if (pos == 1) { v[1] = nv; idx[1] = ni; } else { v[1] = v[0]; idx[1] = idx[0]; } }
    if (pos == 0) { v[0] = nv; idx[0] = ni; }
}

// ---------------- kernel 1: task rms-norm -> task_n fp32 + t_hi/t_lo f16 ----------------
__global__ __launch_bounds__(256) void k_prep_task(const float* __restrict__ task,
                                                   float* __restrict__ task_n,
                                                   f16* __restrict__ t_hi,
                                                   f16* __restrict__ t_lo) {
    __shared__ float sred[8];
    const int row = blockIdx.x;                 // b*NT + t
    const float4* src = (const float4*)(task + (size_t)row * ND);
    const int tid = threadIdx.x;
    float4 v0 = src[tid];
    float4 v1 = src[tid + 256];
    float s = v0.x*v0.x + v0.y*v0.y + v0.z*v0.z + v0.w*v0.w
            + v1.x*v1.x + v1.y*v1.y + v1.z*v1.z + v1.w*v1.w;
    #pragma unroll
    for (int off = 32; off > 0; off >>= 1) s += __shfl_down(s, off, 64);
    if ((tid & 63) == 0) sred[tid >> 6] = s;
    __syncthreads();
    if (tid == 0)
        sred[4] = 1.0f / sqrtf((sred[0]+sred[1]+sred[2]+sred[3]) * (1.0f/ND) + 1e-6f);
    __syncthreads();
    const float inv = sred[4];
    const size_t o = (size_t)row * ND;
    f16x4 h0, l0, h1, l1;
    float4 n0, n1;
    #pragma unroll
    for (int e = 0; e < 4; e++) {
        float f0 = (&v0.x)[e] * inv, f1 = (&v1.x)[e] * inv;
        (&n0.x)[e] = f0; (&n1.x)[e] = f1;
        f16 a = (f16)f0; h0[e] = a; l0[e] = (f16)(f0 - (float)a);
        f16 c = (f16)f1; h1[e] = c; l1[e] = (f16)(f1 - (float)c);
    }
    *(float4*)&task_n[o + tid*4]          = n0;
    *(float4*)&task_n[o + (tid+256)*4]    = n1;
    *(f16x4*)&t_hi[o + tid*4]             = h0;
    *(f16x4*)&t_lo[o + tid*4]             = l0;
    *(f16x4*)&t_hi[o + (tid+256)*4]       = h1;
    *(f16x4*)&t_lo[o + (tid+256)*4]       = l1;
}

// ---------------- kernel 2: R-partials + sumsq (streams patches once, pipelined) ------
// counted-vmcnt pipeline: B stage16 drained with vmcnt(4); A-prefetch (4 loads/wave)
// stays in flight across raw s_barrier + MFMA + next split.
__global__ __launch_bounds__(256) void k_R(const float* __restrict__ patches,
                                           const f16* __restrict__ t_hi,
                                           const f16* __restrict__ t_lo,
                                           float* __restrict__ Rpart,
                                           float* __restrict__ ssqpart) {
    __shared__ __align__(16) char Ah[64*128], Al[64*128];   // 8 KB each
    __shared__ __align__(16) char Bh[48*128], Bl[48*128];   // 6 KB each (28 KB total)
    const int rt = blockIdx.x, ks = blockIdx.y, b = blockIdx.z;
    const int tid = threadIdx.x, wid = tid >> 6, lane = tid & 63;
    const int q15 = lane & 15, g4 = lane >> 4;
    const int trow = tid >> 2, tq = tid & 3;   // A-load: row 0..63, quad pos
    const int lr = lane >> 3, lgch = (lane & 7) ^ lr;
    const int cxor = q15 & 7;

    const float* gP = patches + ((size_t)(b*NN + rt*64))*ND + ks*KS;
    const f16* gTh = t_hi + (size_t)b*NT*ND + ks*KS;
    const f16* gTl = t_lo + (size_t)b*NT*ND + ks*KS;

    f32x4 acc[3];
    #pragma unroll
    for (int j = 0; j < 3; j++) acc[j] = (f32x4){0.f,0.f,0.f,0.f};
    float ssq = 0.f;

    const float* aptr = gP + (size_t)trow*ND + tq*16;
    float4 va[4], vb[4];
    #pragma unroll
    for (int k = 0; k < 4; k++) va[k] = *(const float4*)(aptr + k*4);

    auto body = [&](float4 (&v)[4], float4 (&vn)[4], int kk, bool last) {
        // ---- stage B (tiny, L2-hot): issued FIRST so vmcnt(4) drains exactly these
        #pragma unroll
        for (int t2 = 0; t2 < 2; t2++) {
            const int u = wid + 4*t2;
            if (u < 6) {
                stage16(gTh + (size_t)(u*8 + lr)*ND + kk + lgch*8, Bh + u*1024);
                stage16(gTl + (size_t)(u*8 + lr)*ND + kk + lgch*8, Bl + u*1024);
            }
        }
        __builtin_amdgcn_sched_barrier(0);   // pin issue order: B before A
        // ---- prefetch next A tile (4 load instrs per wave, stay in flight)
        if (!last) {
            #pragma unroll
            for (int k = 0; k < 4; k++)
                vn[k] = *(const float4*)(aptr + kk + 64 + k*4);
        }
        __builtin_amdgcn_sched_barrier(0);
        // ---- split current A regs -> sumsq + f16 hi/lo -> swizzled LDS
        float lssq = 0.f;
        f16x8 hi8[2], lo8[2];
        #pragma unroll
        for (int k = 0; k < 4; k++)
            #pragma unroll
            for (int e = 0; e < 4; e++) {
                const float f = (&v[k].x)[e];
                lssq += f*f;
                const f16 h = (f16)f;
                hi8[k>>1][(k&1)*4 + e] = h;
                lo8[k>>1][(k&1)*4 + e] = (f16)(f - (float)h);
            }
        lssq += __shfl_xor(lssq, 1, 64);
        lssq += __shfl_xor(lssq, 2, 64);
        if (tq == 0) ssq += lssq;
        const int rb = trow * 128;
        #pragma unroll
        for (int c = 0; c < 2; c++) {
            const int ch = (2*tq + c) ^ (trow & 7);
            *(f16x8*)(Ah + rb + ch*16) = hi8[c];
            *(f16x8*)(Al + rb + ch*16) = lo8[c];
        }
        // ---- counted drain: B done, A prefetch still flying
        __builtin_amdgcn_sched_barrier(0);
        if (last) asm volatile("s_waitcnt vmcnt(0)" ::: "memory");
        else      asm volatile("s_waitcnt vmcnt(4)" ::: "memory");
        asm volatile("s_waitcnt lgkmcnt(0)" ::: "memory");
        __builtin_amdgcn_s_barrier();
        __builtin_amdgcn_sched_barrier(0);
        // ---- MFMA: 3 passes hi/lo over the 64-wide K-step
        #pragma unroll
        for (int ksub = 0; ksub < 2; ksub++) {
            const int chb = ((ksub*4 + g4) ^ cxor) << 4;
            const f16x8 a_h = *(const f16x8*)(Ah + (wid*16 + q15)*128 + chb);
            const f16x8 a_l = *(const f16x8*)(Al + (wid*16 + q15)*128 + chb);
            #pragma unroll
            for (int j = 0; j < 3; j++) {
                const f16x8 b_h = *(const f16x8*)(Bh + (j*16 + q15)*128 + chb);
                const f16x8 b_l = *(const f16x8*)(Bl + (j*16 + q15)*128 + chb);
                acc[j] = __builtin_amdgcn_mfma_f32_16x16x32_f16(a_h, b_h, acc[j], 0, 0, 0);
                acc[j] = __builtin_amdgcn_mfma_f32_16x16x32_f16(a_l, b_h, acc[j], 0, 0, 0);
                acc[j] = __builtin_amdgcn_mfma_f32_16x16x32_f16(a_h, b_l, acc[j], 0, 0, 0);
            }
        }
        // raw barrier (LDS reads already consumed into regs before MFMA issue)
        asm volatile("" ::: "memory");
        __builtin_amdgcn_s_barrier();
        __builtin_amdgcn_sched_barrier(0);
    };

    // KS/64 = 8 steps, statically paired (double v-register buffer, rule #20)
    body(va, vb,   0, false);
    body(vb, va,  64, false);
    body(va, vb, 128, false);
    body(vb, va, 192, false);
    body(va, vb, 256, false);
    body(vb, va, 320, false);
    body(va, vb, 384, false);
    body(vb, va, 448, true);

    const int grow = b*NN + rt*64;
    #pragma unroll
    for (int j = 0; j < 3; j++)
        #pragma unroll
        for (int r = 0; r < 4; r++)
            Rpart[((size_t)ks*NROW + grow + wid*16 + g4*4 + r)*48 + j*16 + q15] = acc[j][r];
    if (tq == 0)
        ssqpart[(size_t)ks*NROW + grow + trow] = ssq;
}

// ---------------- kernel 3: combine partials -> pinv, R, w(softmax) ----------------
__global__ __launch_bounds__(256) void k_combine(const float* __restrict__ Rpart,
                                                 const float* __restrict__ ssqpart,
                                                 const int* __restrict__ mask,
                                                 float* __restrict__ R,
                                                 float* __restrict__ w,
                                                 float* __restrict__ pinv) {
    const int r = blockIdx.x * 256 + threadIdx.x;   // 0..12287
    const int b = r / NN;
    float ss = 0.f;
    #pragma unroll
    for (int ks = 0; ks < 4; ks++) ss += ssqpart[(size_t)ks*NROW + r];
    const float pv = 1.0f / sqrtf(ss * (1.0f/ND) + 1e-6f);
    pinv[r] = pv;
    float l[48];
    float mx = -INFINITY;
    #pragma unroll
    for (int t4 = 0; t4 < 12; t4++) {
        float4 a = {0.f,0.f,0.f,0.f};
        #pragma unroll
        for (int ks = 0; ks < 4; ks++) {
            const float4 p = *(const float4*)&Rpart[((size_t)ks*NROW + r)*48 + t4*4];
            a.x += p.x; a.y += p.y; a.z += p.z; a.w += p.w;
        }
        *(float4*)&R[(size_t)r*48 + t4*4] = a;
        #pragma unroll
        for (int e = 0; e < 4; e++) {
            const int t = t4*4 + e;
            const float bias = mask[b*NT + t] ? 0.0f : NEGBIG;
            l[t] = (&a.x)[e] * pv * SCALE + bias;
            mx = fmaxf(mx, l[t]);
        }
    }
    float sum = 0.f;
    #pragma unroll
    for (int t = 0; t < 48; t++) { l[t] = expf(l[t] - mx); sum += l[t]; }
    const float inv = 1.0f / sum;
    #pragma unroll
    for (int t4 = 0; t4 < 12; t4++) {
        float4 o;
        #pragma unroll
        for (int e = 0; e < 4; e++) (&o.x)[e] = l[t4*4 + e] * inv;
        *(float4*)&w[(size_t)r*48 + t4*4] = o;
    }
}

// ---------------- kernel 4: score = pinv[m]*(W.R^T), gated top-4, ILP-4 ---------
__global__ __launch_bounds__(256) void k_scoreW(const float* __restrict__ w,
                                                const float* __restrict__ R,
                                                const float* __restrict__ pinv,
                                                float4* __restrict__ part) {
    __shared__ float Rl[MCH*48];
    __shared__ float pl[MCH];
    const int rt = blockIdx.x, ms = blockIdx.y;
    const int tid = threadIdx.x;
    const int row = rt*256 + tid;
    const int b = row / NN;                 // constant per block (256 | 768)
    const int m0g = b*NN + ms*MCH;
    for (int u = tid; u < MCH*12; u += 256) {
        const int m = u / 12, t4 = u % 12;
        *(float4*)&Rl[m*48 + t4*4] = *(const float4*)&R[((size_t)(m0g + m))*48 + t4*4];
    }
    if (tid < MCH) pl[tid] = pinv[m0g + tid];
    __syncthreads();
    float4 wr[12];
    #pragma unroll
    for (int t4 = 0; t4 < 12; t4++)
        wr[t4] = *(const float4*)&w[(size_t)row*48 + t4*4];
    float tv[4] = {-INFINITY, -INFINITY, -INFINITY, -INFINITY};
    int   ti[4] = {0x7FFFFFFF, 0x7FFFFFFF, 0x7FFFFFFF, 0x7FFFFFFF};
    #pragma unroll 2
    for (int m = 0; m < MCH; m += 4) {
        float s0 = 0.f, s1 = 0.f, s2 = 0.f, s3 = 0.f;
        #pragma unroll
        for (int t4 = 0; t4 < 12; t4++) {
            const float4 r0 = *(const float4*)&Rl[(m+0)*48 + t4*4];
            const float4 r1 = *(const float4*)&Rl[(m+1)*48 + t4*4];
            const float4 r2 = *(const float4*)&Rl[(m+2)*48 + t4*4];
            const float4 r3 = *(const float4*)&Rl[(m+3)*48 + t4*4];
            const float4 wv = wr[t4];
            s0 = fmaf(wv.x, r0.x, s0); s1 = fmaf(wv.x, r1.x, s1);
            s2 = fmaf(wv.x, r2.x, s2); s3 = fmaf(wv.x, r3.x, s3);
            s0 = fmaf(wv.y, r0.y, s0); s1 = fmaf(wv.y, r1.y, s1);
            s2 = fmaf(wv.y, r2.y, s2); s3 = fmaf(wv.y, r3.y, s3);
            s0 = fmaf(wv.z, r0.z, s0); s1 = fmaf(wv.z, r1.z, s1);
            s2 = fmaf(wv.z, r2.z, s2); s3 = fmaf(wv.z, r3.z, s3);
            s0 = fmaf(wv.w, r0.w, s0); s1 = fmaf(wv.w, r1.w, s1);
            s2 = fmaf(wv.w, r2.w, s2); s3 = fmaf(wv.w, r3.w, s3);
        }
        s0 *= pl[m+0]; s1 *= pl[m+1]; s2 *= pl[m+2]; s3 *= pl[m+3];
        // gate: only touch the top-4 if this group can enter it
        const float gm = fmaxf(fmaxf(s0, s1), fmaxf(s2, s3));
        if (gm >= tv[3]) {
            const int mg = ms*MCH + m;
            ins4m(tv, ti, s0, mg+0);
            ins4m(tv, ti, s1, mg+1);
            ins4m(tv, ti, s2, mg+2);
            ins4m(tv, ti, s3, mg+3);
        }
    }
    part[((size_t)row*MSPLIT + ms)*2]     = make_float4(tv[0], __int_as_float(ti[0]), tv[1], __int_as_float(ti[1]));
    part[((size_t)row*MSPLIT + ms)*2 + 1] = make_float4(tv[2], __int_as_float(ti[2]), tv[3], __int_as_float(ti[3]));
}

// ---------------- kernel 5: fused merge + exact rescore + one-hot write ----------
__global__ __launch_bounds__(256) void k_final(const float* __restrict__ patches,
                                               const float* __restrict__ task_n,
                                               const float* __restrict__ w,
                                               const float* __restrict__ pinv,
                                               const float4* __restrict__ part,
                                               float* __restrict__ out) {
    __shared__ float qrow[ND];
    __shared__ float wl[48];
    __shared__ int   scand[64];
    __shared__ float swv[4];
    __shared__ int   swi[4];
    __shared__ int   s_idx, s_cnt;
    const int row = blockIdx.x;
    const int b = row / NN;
    const int tid = threadIdx.x, wid = tid >> 6, lane = tid & 63;

    if (wid == 0) {
        // lane l holds candidate l: chunk l>>2, rank l&3
        const float2 e = ((const float2*)part)[(size_t)row*64 + lane];
        const float myv = e.x;
        const int   myi = __float_as_int(e.y);
        float v = myv; int i = myi;
        #pragma unroll
        for (int off = 1; off <= 32; off <<= 1) {
            const float ov = __shfl_xor(v, off, 64);
            const int   oi = __shfl_xor(i, off, 64);
            if (ov > v || (ov == v && oi < i)) { v = ov; i = oi; }
        }
        const bool in_tau = (myv >= v - TAU);
        const unsigned long long mb  = __ballot(in_tau);
        const unsigned long long mb4 = __ballot(in_tau && ((lane & 3) == 3));
        if (lane == 0) {
            s_idx = i;
            s_cnt = mb4 ? 999 : __popcll(mb);   // chunk 4th within TAU => full scan
        }
        if (in_tau) {
            const unsigned long long below = mb & ((lane == 0) ? 0ull : (~0ull >> (64 - lane)));
            scand[__popcll(below)] = myi;
        }
    }
    __syncthreads();
    const int cnt = s_cnt;
    if (cnt > 1) {
        if (tid < 12) *(float4*)&wl[tid*4] = *(const float4*)&w[(size_t)row*48 + tid*4];
        __syncthreads();
        {   // q = w . task_n (exact fp32), cooperative: thread owns 8 floats
            float q[8] = {0.f,0.f,0.f,0.f,0.f,0.f,0.f,0.f};
            for (int t = 0; t < NT; t++) {
                const float wt = wl[t];
                const float* Tn = task_n + ((size_t)(b*NT + t))*ND + tid*8;
                const float4 u0 = *(const float4*)Tn;
                const float4 u1 = *(const float4*)(Tn + 4);
                q[0] = fmaf(wt, u0.x, q[0]); q[1] = fmaf(wt, u0.y, q[1]);
                q[2] = fmaf(wt, u0.z, q[2]); q[3] = fmaf(wt, u0.w, q[3]);
                q[4] = fmaf(wt, u1.x, q[4]); q[5] = fmaf(wt, u1.y, q[5]);
                q[6] = fmaf(wt, u1.z, q[6]); q[7] = fmaf(wt, u1.w, q[7]);
            }
            #pragma unroll
            for (int e2 = 0; e2 < 8; e2++) qrow[tid*8 + e2] = q[e2];
        }
        __syncthreads();
        float bw = -INFINITY; int bi = 0x7FFFFFFF;
        if (cnt != 999) {
            for (int c = wid; c < cnt; c += 4) {
                const int m = scand[c];
                const float* prow = patches + ((size_t)b*NN + m)*ND + lane*32;
                const float* qp = qrow + lane*32;
                float s = 0.f;
                #pragma unroll
                for (int k = 0; k < 8; k++) {
                    const float4 p = *(const float4*)(prow + k*4);
                    const float4 qv = *(const float4*)(qp + k*4);
                    s = fmaf(p.x, qv.x, s); s = fmaf(p.y, qv.y, s);
                    s = fmaf(p.z, qv.z, s); s = fmaf(p.w, qv.w, s);
                }
                #pragma unroll
                for (int off = 32; off > 0; off >>= 1) s += __shfl_down(s, off, 64);
                if (lane == 0) {
                    s *= pinv[b*NN + m];
                    if (s > bw || (s == bw && m < bi)) { bw = s; bi = m; }
                }
            }
        } else {
            for (int m = wid; m < NN; m += 4) {
                const float* prow = patches + ((size_t)b*NN + m)*ND + lane*32;
                const float* qp = qrow + lane*32;
                float s = 0.f;
                #pragma unroll
                for (int k = 0; k < 8; k++) {
                    const float4 p = *(const float4*)(prow + k*4);
                    const float4 qv = *(const float4*)(qp + k*4);
                    s = fmaf(p.x, qv.x, s); s = fmaf(p.y, qv.y, s);
                    s = fmaf(p.z, qv.z, s); s = fmaf(p.w, qv.w, s);
                }
                #pragma unroll
                for (int off = 32; off > 0; off >>= 1) s += __shfl_down(s, off, 64);
                if (lane == 0) {
                    s *= pinv[b*NN + m];
                    if (s > bw || (s == bw && m < bi)) { bw = s; bi = m; }
                }
            }
        }
        if (lane == 0) { swv[wid] = bw; swi[wid] = bi; }
        __syncthreads();
        if (tid == 0) {
            float v = swv[0]; int i = swi[0];
            #pragma unroll
            for (int k = 1; k < 4; k++) {
                if (swv[k] > v || (swv[k] == v && swi[k] < i)) { v = swv[k]; i = swi[k]; }
            }
            s_idx = i;
        }
        __syncthreads();
    }
    // one-hot write: 192 float4 per row
    const int m = s_idx;
    if (tid < 192) {
        float4 o = {0.f, 0.f, 0.f, 0.f};
        if ((m >> 2) == tid) ((float*)&o)[m & 3] = 1.0f;
        ((float4*)(out + (size_t)row*NN))[tid] = o;
    }
}

// ---------------- launcher ----------------
extern "C" void kernel_launch(void* const* d_in, const int* in_sizes, int n_in,
                              void* d_out, int out_size, void* d_ws, size_t ws_size,
                              hipStream_t stream) {
    const float* patches = (const float*)d_in[0];
    const float* task    = (const float*)d_in[1];
    const int*   mask    = (const int*)d_in[2];
    float* out = (float*)d_out;

    char* p = (char*)d_ws;
    float* task_n  = (float*)p;  p += (size_t)NB*NT*ND*sizeof(float);    // 6.29 MB
    f16*   t_hi    = (f16*)p;    p += (size_t)NB*NT*ND*sizeof(f16);      // 3.15 MB
    f16*   t_lo    = (f16*)p;    p += (size_t)NB*NT*ND*sizeof(f16);      // 3.15 MB
    float* Rpart   = (float*)p;  p += (size_t)4*NROW*48*sizeof(float);   // 9.44 MB
    float* ssqpart = (float*)p;  p += (size_t)4*NROW*sizeof(float);      // 197 KB
    float* R       = (float*)p;  p += (size_t)NROW*48*sizeof(float);     // 2.36 MB
    float* w       = (float*)p;  p += (size_t)NROW*48*sizeof(float);     // 2.36 MB
    float* pinv    = (float*)p;  p += (size_t)NROW*sizeof(float);        // 49 KB
    float4* part   = (float4*)p; p += (size_t)NROW*MSPLIT*2*sizeof(float4); // 6.3 MB

    k_prep_task<<<NB*NT, 256, 0, stream>>>(task, task_n, t_hi, t_lo);
    k_R<<<dim3(NN/64, 4, NB), 256, 0, stream>>>(patches, t_hi, t_lo, Rpart, ssqpart);
    k_combine<<<NROW/256, 256, 0, stream>>>(Rpart, ssqpart, mask, R, w, pinv);
    k_scoreW<<<dim3(NROW/256, MSPLIT), 256, 0, stream>>>(w, R, pinv, part);
    k_final<<<NROW, 256, 0, stream>>>(patches, task_n, w, pinv, part, out);
}